// Round 1
// baseline (6663.917 us; speedup 1.0000x reference)
//
#include <hip/hip_runtime.h>

// Handwriting synthesis RNN — persistent fused kernel, R4.
// R4 vs R3: latency-chain surgery. (1) fan-in halved: role0 8 blocks/group
// (4 acc cols, 288 weight VGPRs), role1 16 blocks/group (2 acc cols) —
// max-of-N straggler tail and ring traffic halve. (2) atomic arrive counters
// replaced by per-block tag slots (plain sc0sc1 stores, monotone step tags);
// waiters do ONE lane-indexed load over 26 slots + __all() ballot.
// (3) all threads poll (no tid0+barrier hop); strks load hoisted above poll.
// (4) gate LDS layout -> [4][16][C+1] planes: conflict-free gate reads
// (was 8-way), unioned with pp/phi to stay <64KB LDS.

typedef unsigned short u16;
typedef unsigned int   u32;
typedef unsigned long long u64;
typedef u16   u16x8  __attribute__((ext_vector_type(8)));
typedef __bf16 bf16x8 __attribute__((ext_vector_type(8)));
typedef float f32x4  __attribute__((ext_vector_type(4)));

#define DEV static __device__ __forceinline__

// problem constants
#define BT   64
#define TT   800
#define UU   64
#define HH   512
#define SENT 60
#define NG   2048
#define MOUT 121
#define K1P 576    // X1 = [h1:512][strk:3][w:60][pad:1]
#define K2P 1088   // X2 = [h1:512][h2:512][strk:3][w:60][pad:1]
#define KMD 1024   // Xm = [h1:512][h2:512]
#define KSW 512

#define NBG 4
#define G1B 8
#define G2B 16
#define MDB 2
#define NBLK (NBG*(G1B+G2B+MDB))   // 104

// workspace layout (bytes)
#define OFF_BAR 0
#define OFF_H1  4096
#define OFF_H2  (OFF_H1 + 4*BT*HH*2)
#define OFF_CM  (OFF_H2 + 4*BT*HH*2)
#define OFF_W1  (OFF_CM + 32768)
#define OFF_W2  (OFF_W1 + NG*K1P*2)
#define OFF_WSW (OFF_W2 + NG*K2P*2)
#define OFF_WMD (OFF_WSW + 32*KSW*2)
#define OFF_B1  (OFF_WMD + 128*KMD*2)
#define OFF_B2  (OFF_B1 + NG*4)
#define OFF_BSW (OFF_B2 + NG*4)
#define OFF_BMD (OFF_BSW + 256)
#define WS_NEED (OFF_BMD + 512)
#define ZERO_BYTES OFF_CM   // slots + h1/h2 rings

// output offsets (floats)
#define OW_EOS 0
#define OW_W   (BT*TT)
#define OW_MU1 (OW_W   + BT*TT*20)
#define OW_MU2 (OW_MU1 + BT*TT*20)
#define OW_S1  (OW_MU2 + BT*TT*20)
#define OW_S2  (OW_S1  + BT*TT*20)
#define OW_RHO (OW_S2  + BT*TT*20)

DEV u16 f2bf(float f){
  u32 u = __builtin_bit_cast(u32, f);
  u = (u + 0x7FFFu + ((u >> 16) & 1u)) >> 16;
  return (u16)u;
}
DEV bf16x8 ld8(const u16* p){ return __builtin_bit_cast(bf16x8, *(const u16x8*)p); }
DEV f32x4 mfma16(bf16x8 a, bf16x8 b, f32x4 c){
  return __builtin_amdgcn_mfma_f32_16x16x32_bf16(a, b, c, 0, 0, 0);
}
DEV float sig_(float x){ return 1.f/(1.f + __expf(-x)); }
DEV float tanh_(float x){
  float ax = fabsf(x);
  float e  = __expf(-2.f*ax);
  float t2 = (1.f - e)/(1.f + e);
  return x < 0.f ? -t2 : t2;
}

// ---- L3-coherent (device-scope) memory helpers ----
DEV void ld_tile4(const u16* p, u16x8& a0, u16x8& a1, u16x8& a2, u16x8& a3){
  asm volatile(
    "global_load_dwordx4 %0, %4, off sc0 sc1\n\t"
    "global_load_dwordx4 %1, %4, off offset:256 sc0 sc1\n\t"
    "global_load_dwordx4 %2, %4, off offset:512 sc0 sc1\n\t"
    "global_load_dwordx4 %3, %4, off offset:768 sc0 sc1\n\t"
    "s_waitcnt vmcnt(0)"
    : "=&v"(a0), "=&v"(a1), "=&v"(a2), "=&v"(a3)
    : "v"(p) : "memory");
}
DEV void ld_tile8(const u16* p1, const u16* p2,
                  u16x8& a0,u16x8& a1,u16x8& a2,u16x8& a3,
                  u16x8& b0,u16x8& b1,u16x8& b2,u16x8& b3){
  asm volatile(
    "global_load_dwordx4 %0, %8, off sc0 sc1\n\t"
    "global_load_dwordx4 %1, %8, off offset:256 sc0 sc1\n\t"
    "global_load_dwordx4 %2, %8, off offset:512 sc0 sc1\n\t"
    "global_load_dwordx4 %3, %8, off offset:768 sc0 sc1\n\t"
    "global_load_dwordx4 %4, %9, off sc0 sc1\n\t"
    "global_load_dwordx4 %5, %9, off offset:256 sc0 sc1\n\t"
    "global_load_dwordx4 %6, %9, off offset:512 sc0 sc1\n\t"
    "global_load_dwordx4 %7, %9, off offset:768 sc0 sc1\n\t"
    "s_waitcnt vmcnt(0)"
    : "=&v"(a0),"=&v"(a1),"=&v"(a2),"=&v"(a3),
      "=&v"(b0),"=&v"(b1),"=&v"(b2),"=&v"(b3)
    : "v"(p1), "v"(p2) : "memory");
}
DEV void st_short_sc(u16* p, u32 v){
  asm volatile("global_store_short %0, %1, off sc0 sc1" :: "v"(p), "v"(v) : "memory");
}
DEV void vmwait0(){ asm volatile("s_waitcnt vmcnt(0)" ::: "memory"); }

// tag-slot barrier: per group, 32 u32 slots at bar+bg*32.
//   [0..7]  role0 blocks, [8..23] role1 blocks, [24..25] role2 blocks.
// Producer stores step+1 (monotone, never reset). Waiters: one lane-indexed
// load over the slots + __all() ballot. Store-after-vmcnt(0) ordering
// guarantees: tag visible => that block's ring data is in L3.
DEV void poll_slots(const u32* slots, int T0, int T1, int T2){
  if (T0 <= 0 && T1 <= 0 && T2 <= 0) return;
  const int lane = threadIdx.x & 63;
  int thr;
  if (lane < 8)       thr = T0;
  else if (lane < 24) thr = T1;
  else if (lane < 26) thr = T2;
  else                thr = (int)0x80000000;   // always passes
  const u32* p = slots + (lane < 26 ? lane : 31);
  for(;;){
    u32 v;
    asm volatile("global_load_dword %0, %1, off sc0 sc1\n\ts_waitcnt vmcnt(0)"
      : "=&v"(v) : "v"(p) : "memory");
    if (__all((int)v >= thr)) return;
    __builtin_amdgcn_s_sleep(1);
  }
}
DEV void publish(u32* p, int v){
  asm volatile("global_store_dword %0, %1, off sc0 sc1" :: "v"(p), "v"((u32)v) : "memory");
}

// ---------------- weight/bias/mask pre-pack (unchanged) ----------
__global__ __launch_bounds__(256) void pack_kernel(
    const float* __restrict__ Wih1, const float* __restrict__ Whh1,
    const float* __restrict__ bih1, const float* __restrict__ bhh1,
    const float* __restrict__ Wih2, const float* __restrict__ Whh2,
    const float* __restrict__ bih2, const float* __restrict__ bhh2,
    const float* __restrict__ Wsw,  const float* __restrict__ bsw,
    const float* __restrict__ Wmdn, const float* __restrict__ bmdn,
    const float* __restrict__ onehots, char* __restrict__ ws)
{
  u16* Wp1  = (u16*)(ws + OFF_W1);
  u16* Wp2  = (u16*)(ws + OFF_W2);
  u16* Wswp = (u16*)(ws + OFF_WSW);
  u16* Wmdp = (u16*)(ws + OFF_WMD);
  float* b1p  = (float*)(ws + OFF_B1);
  float* b2p  = (float*)(ws + OFF_B2);
  float* bswp = (float*)(ws + OFF_BSW);
  float* bmdp = (float*)(ws + OFF_BMD);
  u64* cmask = (u64*)(ws + OFF_CM);

  const int SA = NG*K1P, SB = NG*K2P, SC = 32*KSW, SD = 128*KMD;
  const int SE = NG + NG + 32 + 128, SF = BT*SENT;
  const int total = SA+SB+SC+SD+SE+SF;
  for (int i = blockIdx.x*blockDim.x + threadIdx.x; i < total; i += gridDim.x*blockDim.x){
    if (i < SA){
      const int n = i / K1P, k = i - n*K1P;
      const int r = (n&3)*HH + (n>>2);
      float f;
      if (k < 512)      f = Whh1[r*HH + k];
      else if (k < 515) f = Wih1[r*63 + (k-512)];
      else if (k < 575) f = Wih1[r*63 + 3 + (k-515)];
      else              f = 0.f;
      Wp1[i] = f2bf(f);
    } else if (i < SA+SB){
      const int j = i - SA;
      const int n = j / K2P, k = j - n*K2P;
      const int r = (n&3)*HH + (n>>2);
      float f;
      if (k < 512)       f = Wih2[r*575 + 3 + k];
      else if (k < 1024) f = Whh2[r*HH + (k-512)];
      else if (k < 1027) f = Wih2[r*575 + (k-1024)];
      else if (k < 1087) f = Wih2[r*575 + 515 + (k-1027)];
      else               f = 0.f;
      Wp2[j] = f2bf(f);
    } else if (i < SA+SB+SC){
      const int j = i - SA - SB;
      const int n = j >> 9, k = j & 511;
      Wswp[j] = f2bf(n < 30 ? Wsw[n*KSW + k] : 0.f);
    } else if (i < SA+SB+SC+SD){
      const int j = i - SA - SB - SC;
      const int n = j >> 10, k = j & 1023;
      float f = 0.f;
      if (n < MOUT) f = (k < 512) ? Wmdn[n*1536 + k]
                                  : (Wmdn[n*1536 + 512 + (k-512)] + Wmdn[n*1536 + 1024 + (k-512)]);
      Wmdp[j] = f2bf(f);
    } else if (i < SA+SB+SC+SD+SE){
      int j = i - SA - SB - SC - SD;
      if (j < NG){ const int r=(j&3)*HH+(j>>2); b1p[j] = bih1[r] + bhh1[r]; }
      else if ((j -= NG) < NG){ const int r=(j&3)*HH+(j>>2); b2p[j] = bih2[r] + bhh2[r]; }
      else if ((j -= NG) < 32){ bswp[j] = (j < 30) ? bsw[j] : 0.f; }
      else { j -= 32; bmdp[j] = (j < MOUT) ? bmdn[j] : 0.f; }
    } else {
      const int j = i - SA - SB - SC - SD - SE;
      const int b = j / SENT, c = j - b*SENT;
      const float* oh = onehots + b*UU*SENT + c;
      u64 m = 0;
#pragma unroll 1
      for (int u = 0; u < UU; ++u) if (oh[u*SENT] > 0.5f) m |= (1ull << u);
      cmask[j] = m;
    }
  }
}

// ---------------- LDS layouts ----------------
// gates planes: [4 gates][16 rows][C+1 cols] — reads (consecutive col per
// lane) are conflict-free; writes ~2-way. gates unioned with pp/phi
// (disjoint lifetimes within a step).
struct G1S {
  float c[1024]; float kk[160];
  u16   X1[16*584];
  union { float gates[4*16*65]; struct { float pp[1024]; float phi[1024]; } a; } u;
  float aa[160], bb[160];
  float smv[1024];
  u64   cm[960];
};
struct G2S {
  float c[512]; float kk[160];
  u16   X2[16*1096];
  union { float gates[4*16*33]; struct { float pp[1024]; float phi[1024]; } a; } u;
  float aa[160], bb[160];
  float smv[1024];
  u64   cm[960];
};
struct MDS { u16 X[16*1032]; float par[16*68]; };
union alignas(16) BigU { G1S g1; G2S g2; MDS md; };

struct WswF { bf16x8 f[8]; };   // by-value => stays in VGPRs after inlining

// attention for step (tw-1): p = h1 @ Wsw^T from staged X (cols 0..511),
// kappa accumulates in kk (private per-block), writes bf16 w directly into
// the X tile tail at tailoff. tw==0 => copy wprev into tail.
DEV void attn_tail(int tw, int bg, u16* X, int xstride, int tailoff,
                   float* pp, float* aa, float* bb, float* kk, float* phi,
                   const float* smv, const u64* cmL, WswF wf,
                   float bswa, float bswb, float bswk,
                   const float* __restrict__ wprev)
{
  const int tid = threadIdx.x;
  if (tw == 0){
    for (int i = tid; i < 16*SENT; i += 256){
      const int b = i / SENT, c = i - b*SENT;
      X[b*xstride + tailoff + c] = f2bf(wprev[(bg*16 + b)*SENT + c]);
    }
    return;
  }
  const int wave = tid >> 6, lane = tid & 63;
  const int quad = lane >> 4, l15 = lane & 15;
  {
    f32x4 acc = {0.f,0.f,0.f,0.f};
    const u16* ap = X + l15*xstride + quad*8 + (wave>>1)*256;
#pragma unroll
    for (int j = 0; j < 8; ++j) acc = mfma16(ld8(ap + j*32), wf.f[j], acc);
    float* dst = pp + (wave>>1)*512;
    const int n = (wave&1)*16 + l15;
#pragma unroll
    for (int r = 0; r < 4; ++r) dst[(quad*4 + r)*32 + n] = acc[r];
  }
  __syncthreads();
  if (tid < 160){
    const int b = tid/10, j = tid - b*10;
    aa[tid] = __expf(pp[b*32 + j]      + pp[512 + b*32 + j]      + bswa);
    bb[tid] = __expf(pp[b*32 + 10 + j] + pp[512 + b*32 + 10 + j] + bswb);
    kk[tid] += __expf(pp[b*32 + 20 + j] + pp[512 + b*32 + 20 + j] + bswk);
  }
  __syncthreads();
  for (int i = tid; i < 1024; i += 256){
    const int b = i >> 6, u = i & 63;
    const float uf = (float)u;
    float acc = 0.f;
#pragma unroll
    for (int j = 0; j < 10; ++j){
      float d = kk[b*10 + j] - uf;
      acc = fmaf(aa[b*10 + j], __expf(-bb[b*10 + j]*d*d), acc);
    }
    phi[i] = acc * smv[i];
  }
  __syncthreads();
  for (int i = tid; i < 16*SENT; i += 256){
    const int b = i / SENT, c = i - b*SENT;
    u64 m = cmL[i];
    float acc = 0.f;
    while (m){ const int u = __builtin_ctzll(m); m &= m - 1; acc += phi[b*64 + u]; }
    X[b*xstride + tailoff + c] = f2bf(acc);
  }
}

// ---------------- main persistent kernel ----------------
__global__ __launch_bounds__(256, 1) void rnn_main(
    const float* __restrict__ strks, const float* __restrict__ sm,
    const float* __restrict__ wprev, char* __restrict__ ws,
    float* __restrict__ out)
{
  u32* bar   = (u32*)(ws + OFF_BAR);
  u16* h1pub = (u16*)(ws + OFF_H1);
  u16* h2pub = (u16*)(ws + OFF_H2);
  const u64* cmask = (const u64*)(ws + OFF_CM);
  const u16* Wp1  = (const u16*)(ws + OFF_W1);
  const u16* Wp2  = (const u16*)(ws + OFF_W2);
  const u16* Wswp = (const u16*)(ws + OFF_WSW);
  const u16* Wmdp = (const u16*)(ws + OFF_WMD);
  const float* b1p  = (const float*)(ws + OFF_B1);
  const float* b2p  = (const float*)(ws + OFF_B2);
  const float* bswp = (const float*)(ws + OFF_BSW);
  const float* bmdp = (const float*)(ws + OFF_BMD);

  __shared__ BigU S;

  const int bid = blockIdx.x, tid = threadIdx.x;
  const int wave = tid >> 6, lane = tid & 63;
  const int quad = lane >> 4, l15 = lane & 15;
  const int sb = tid >> 4, sl = tid & 15;

  if (bid < NBG*G1B){
    // ============ role 0: LSTM1 step t; 8 blocks/group, 256 gate cols each
    const int bg = bid >> 3, s = bid & 7;
    u32* slots = bar + bg*32;
    bf16x8 w1r[72];
    const int nb = s*256 + wave*64 + l15;
#pragma unroll
    for (int kt = 0; kt < 18; ++kt){
#pragma unroll
      for (int u = 0; u < 4; ++u)
        w1r[4*kt+u] = ld8(Wp1 + (nb + 16*u)*K1P + quad*8 + kt*32);
    }
    WswF wf;
    { const int nsw = (wave&1)*16 + l15, k0 = (wave>>1)*8;
#pragma unroll
      for (int j = 0; j < 8; ++j) wf.f[j] = ld8(Wswp + nsw*KSW + quad*8 + (k0+j)*32);
    }
    const float bias0 = b1p[nb], bias1 = b1p[nb+16], bias2 = b1p[nb+32], bias3 = b1p[nb+48];
    float bswa = 0.f, bswb = 0.f, bswk = 0.f;
    if (tid < 160){ const int j = tid % 10; bswa = bswp[j]; bswb = bswp[10+j]; bswk = bswp[20+j]; }
    for (int i = tid; i < 1024; i += 256) S.g1.c[i] = 0.f;
    if (tid < 160) S.g1.kk[tid] = 0.f;
    for (int i = tid; i < 1024; i += 256) S.g1.smv[i] = sm[(bg*16 + (i>>6))*UU + (i&63)];
    for (int i = tid; i < 960;  i += 256) S.g1.cm[i]  = cmask[(bg*16 + i/60)*SENT + i%60];
    if (sl == 0) S.g1.X1[sb*584 + 575] = 0;
    __syncthreads();

    for (int t = 0; t < TT; ++t){
      float sv = (sl < 3) ? strks[((bg*16 + sb)*TT + t)*3 + sl] : 0.f;
      poll_slots(slots, t, t-3, t-3);
      const u16* h1prev = h1pub + ((t+3)&3)*(BT*HH);
      {
        u16x8 a0,a1,a2,a3;
        ld_tile4(h1prev + (bg*16 + sb)*HH + sl*8, a0,a1,a2,a3);
        u16x8* xr = (u16x8*)(S.g1.X1 + sb*584);
        xr[sl] = a0; xr[sl+16] = a1; xr[sl+32] = a2; xr[sl+48] = a3;
        if (sl < 3) S.g1.X1[sb*584 + 512 + sl] = f2bf(sv);
      }
      __syncthreads();
      attn_tail(t, bg, S.g1.X1, 584, 515, S.g1.u.a.pp, S.g1.aa, S.g1.bb, S.g1.kk,
                S.g1.u.a.phi, S.g1.smv, S.g1.cm, wf, bswa, bswb, bswk, wprev);
      __syncthreads();
      f32x4 acc0 = {0.f,0.f,0.f,0.f}, acc1 = {0.f,0.f,0.f,0.f};
      f32x4 acc2 = {0.f,0.f,0.f,0.f}, acc3 = {0.f,0.f,0.f,0.f};
      const u16* ap = S.g1.X1 + l15*584 + quad*8;
#pragma unroll
      for (int kt = 0; kt < 18; ++kt){
        bf16x8 av = ld8(ap + kt*32);
        acc0 = mfma16(av, w1r[4*kt+0], acc0);
        acc1 = mfma16(av, w1r[4*kt+1], acc1);
        acc2 = mfma16(av, w1r[4*kt+2], acc2);
        acc3 = mfma16(av, w1r[4*kt+3], acc3);
      }
      {
        const int gpl = l15 & 3, cbase = wave*16 + (l15 >> 2);
#pragma unroll
        for (int r = 0; r < 4; ++r){
          float* gp = S.g1.u.gates + gpl*1040 + (quad*4 + r)*65 + cbase;
          gp[0]  = acc0[r] + bias0;
          gp[4]  = acc1[r] + bias1;
          gp[8]  = acc2[r] + bias2;
          gp[12] = acc3[r] + bias3;
        }
      }
      __syncthreads();
      u16* h1cur = h1pub + (t&3)*(BT*HH);
      for (int i = tid; i < 1024; i += 256){
        const int row = i >> 6, col = i & 63;
        const float* gb = S.g1.u.gates + row*65 + col;
        const float vi = gb[0], vf = gb[1040], vg = gb[2080], vo = gb[3120];
        float c = sig_(vf)*S.g1.c[i] + sig_(vi)*tanh_(vg);
        S.g1.c[i] = c;
        st_short_sc(h1cur + (bg*16 + row)*HH + s*64 + col, (u32)f2bf(sig_(vo)*tanh_(c)));
      }
      vmwait0();
      __syncthreads();
      if (tid == 0) publish(slots + s, t+1);
    }
  }
  else if (bid < NBG*(G1B+G2B)){
    // ============ role 1: LSTM2 step te; 16 blocks/group, 128 gate cols each
    const int b2 = bid - NBG*G1B, bg = b2 >> 4, s = b2 & 15;
    u32* slots = bar + bg*32;
    bf16x8 w2r[68];
    const int n0 = s*128 + wave*32 + l15;
#pragma unroll
    for (int kt = 0; kt < 34; ++kt){
      w2r[2*kt]   = ld8(Wp2 + n0*K2P + quad*8 + kt*32);
      w2r[2*kt+1] = ld8(Wp2 + (n0+16)*K2P + quad*8 + kt*32);
    }
    WswF wf;
    { const int nsw = (wave&1)*16 + l15, k0 = (wave>>1)*8;
#pragma unroll
      for (int j = 0; j < 8; ++j) wf.f[j] = ld8(Wswp + nsw*KSW + quad*8 + (k0+j)*32);
    }
    const float bias0 = b2p[n0], bias1 = b2p[n0+16];
    float bswa = 0.f, bswb = 0.f, bswk = 0.f;
    if (tid < 160){ const int j = tid % 10; bswa = bswp[j]; bswb = bswp[10+j]; bswk = bswp[20+j]; }
    for (int i = tid; i < 512; i += 256) S.g2.c[i] = 0.f;
    if (tid < 160) S.g2.kk[tid] = 0.f;
    for (int i = tid; i < 1024; i += 256) S.g2.smv[i] = sm[(bg*16 + (i>>6))*UU + (i&63)];
    for (int i = tid; i < 960;  i += 256) S.g2.cm[i]  = cmask[(bg*16 + i/60)*SENT + i%60];
    if (sl == 0) S.g2.X2[sb*1096 + 1087] = 0;
    __syncthreads();

    for (int te = 0; te < TT; ++te){
      float sv = (sl < 3) ? strks[((bg*16 + sb)*TT + te)*3 + sl] : 0.f;
      poll_slots(slots, te+1, te, te-3);
      const u16* h1te = h1pub + (te&3)*(BT*HH);
      const u16* h2pv = h2pub + ((te+3)&3)*(BT*HH);
      {
        u16x8 a0,a1,a2,a3,b0,b1,b2v,b3;
        ld_tile8(h1te + (bg*16 + sb)*HH + sl*8, h2pv + (bg*16 + sb)*HH + sl*8,
                 a0,a1,a2,a3, b0,b1,b2v,b3);
        u16x8* xr = (u16x8*)(S.g2.X2 + sb*1096);
        xr[sl] = a0; xr[sl+16] = a1; xr[sl+32] = a2; xr[sl+48] = a3;
        xr[64+sl] = b0; xr[64+sl+16] = b1; xr[64+sl+32] = b2v; xr[64+sl+48] = b3;
        if (sl < 3) S.g2.X2[sb*1096 + 1024 + sl] = f2bf(sv);
      }
      __syncthreads();
      attn_tail(te+1, bg, S.g2.X2, 1096, 1027, S.g2.u.a.pp, S.g2.aa, S.g2.bb, S.g2.kk,
                S.g2.u.a.phi, S.g2.smv, S.g2.cm, wf, bswa, bswb, bswk, wprev);
      __syncthreads();
      f32x4 acc0 = {0.f,0.f,0.f,0.f}, acc1 = {0.f,0.f,0.f,0.f};
      const u16* ap = S.g2.X2 + l15*1096 + quad*8;
#pragma unroll
      for (int kt = 0; kt < 34; ++kt){
        bf16x8 av = ld8(ap + kt*32);
        acc0 = mfma16(av, w2r[2*kt],   acc0);
        acc1 = mfma16(av, w2r[2*kt+1], acc1);
      }
      {
        const int gpl = l15 & 3, cbase = wave*8 + (l15 >> 2);
#pragma unroll
        for (int r = 0; r < 4; ++r){
          float* gp = S.g2.u.gates + gpl*528 + (quad*4 + r)*33 + cbase;
          gp[0] = acc0[r] + bias0;
          gp[4] = acc1[r] + bias1;
        }
      }
      __syncthreads();
      u16* h2cur = h2pub + (te&3)*(BT*HH);
      for (int i = tid; i < 512; i += 256){
        const int row = i >> 5, col = i & 31;
        const float* gb = S.g2.u.gates + row*33 + col;
        const float vi = gb[0], vf = gb[528], vg = gb[1056], vo = gb[1584];
        float c = sig_(vf)*S.g2.c[i] + sig_(vi)*tanh_(vg);
        S.g2.c[i] = c;
        st_short_sc(h2cur + (bg*16 + row)*HH + s*32 + col, (u32)f2bf(sig_(vo)*tanh_(c)));
      }
      vmwait0();
      __syncthreads();
      if (tid == 0) publish(slots + 8 + s, te+1);
    }
  }
  else {
    // ============ role 2: MDN head, step te (signals after staging) ====
    const int b2 = bid - NBG*(G1B+G2B), bg = b2 >> 1, s = b2 & 1;
    u32* slots = bar + bg*32;
    bf16x8 wmr[32];
    const int n0 = s*64 + wave*16 + l15;
#pragma unroll
    for (int kt = 0; kt < 32; ++kt) wmr[kt] = ld8(Wmdp + n0*KMD + quad*8 + kt*32);
    const float bias0 = bmdp[n0];
    __syncthreads();

    for (int te = 0; te < TT; ++te){
      poll_slots(slots, 0, te+1, 0);
      const u16* h1te = h1pub + (te&3)*(BT*HH);
      const u16* h2te = h2pub + (te&3)*(BT*HH);
      {
        u16x8 a0,a1,a2,a3,b0,b1,b2v,b3;
        ld_tile8(h1te + (bg*16 + sb)*HH + sl*8, h2te + (bg*16 + sb)*HH + sl*8,
                 a0,a1,a2,a3, b0,b1,b2v,b3);
        u16x8* xr = (u16x8*)(S.md.X + sb*1032);
        xr[sl] = a0; xr[sl+16] = a1; xr[sl+32] = a2; xr[sl+48] = a3;
        xr[64+sl] = b0; xr[64+sl+16] = b1; xr[64+sl+32] = b2v; xr[64+sl+48] = b3;
      }
      __syncthreads();
      if (tid == 0) publish(slots + 24 + s, te+1);   // ring reads done
      f32x4 acc = {0.f,0.f,0.f,0.f};
      const u16* ap = S.md.X + l15*1032 + quad*8;
#pragma unroll
      for (int kt = 0; kt < 32; ++kt) acc = mfma16(ld8(ap + kt*32), wmr[kt], acc);
#pragma unroll
      for (int r = 0; r < 4; ++r)
        S.md.par[(quad*4 + r)*68 + wave*16 + l15] = acc[r] + bias0;
      __syncthreads();
      for (int i = tid; i < 1024; i += 256){
        const int b = i >> 6, lc = i & 63, gc = s*64 + lc;
        const int bt = (bg*16 + b)*TT + te;
        const float v = S.md.par[b*68 + lc];
        if (gc >= 20 && gc < 40)        out[OW_MU1 + bt*20 + (gc-20)]  = v;
        else if (gc >= 40 && gc < 60)   out[OW_MU2 + bt*20 + (gc-40)]  = v;
        else if (gc >= 60 && gc < 80)   out[OW_S1  + bt*20 + (gc-60)]  = __expf(v);
        else if (gc >= 80 && gc < 100)  out[OW_S2  + bt*20 + (gc-80)]  = __expf(v);
        else if (gc >= 100 && gc < 120) out[OW_RHO + bt*20 + (gc-100)] = tanh_(v);
        else if (gc == 120)             out[OW_EOS + bt]               = sig_(v);
      }
      if (s == 0 && tid < 16){
        const int b = tid;
        const int bt = (bg*16 + b)*TT + te;
        float mx = -1e30f;
        for (int c = 0; c < 20; ++c) mx = fmaxf(mx, S.md.par[b*68 + c]);
        float sum = 0.f;
        for (int c = 0; c < 20; ++c) sum += __expf(S.md.par[b*68 + c] - mx);
        const float inv = 1.f/sum;
        for (int c = 0; c < 20; ++c)
          out[OW_W + bt*20 + c] = __expf(S.md.par[b*68 + c] - mx)*inv;
      }
    }
  }
}

extern "C" void kernel_launch(void* const* d_in, const int* in_sizes, int n_in,
                              void* d_out, int out_size, void* d_ws, size_t ws_size,
                              hipStream_t stream)
{
  const float* strks   = (const float*)d_in[0];
  const float* sentsm  = (const float*)d_in[3];
  const float* onehots = (const float*)d_in[4];
  const float* wprev   = (const float*)d_in[5];
  const float* Wih1 = (const float*)d_in[6];
  const float* Whh1 = (const float*)d_in[7];
  const float* bih1 = (const float*)d_in[8];
  const float* bhh1 = (const float*)d_in[9];
  const float* Wih2 = (const float*)d_in[10];
  const float* Whh2 = (const float*)d_in[11];
  const float* bih2 = (const float*)d_in[12];
  const float* bhh2 = (const float*)d_in[13];
  const float* Wsw  = (const float*)d_in[14];
  const float* bsw  = (const float*)d_in[15];
  const float* Wmdn = (const float*)d_in[16];
  const float* bmdn = (const float*)d_in[17];
  (void)in_sizes; (void)n_in; (void)out_size;

  if (ws_size < (size_t)WS_NEED) return;

  hipMemsetAsync(d_ws, 0, ZERO_BYTES, stream);
  pack_kernel<<<2048, 256, 0, stream>>>(Wih1, Whh1, bih1, bhh1, Wih2, Whh2, bih2, bhh2,
                                        Wsw, bsw, Wmdn, bmdn, onehots, (char*)d_ws);
  rnn_main<<<NBLK, 256, 0, stream>>>(strks, sentsm, wprev, (char*)d_ws, (float*)d_out);
}

// Round 2
// 5844.970 us; speedup vs baseline: 1.1401x; 1.1401x over previous
//
#include <hip/hip_runtime.h>

// Handwriting synthesis RNN — persistent fused kernel, R5.
// R5 vs R4 post-mortem: R4's fan-in halving doubled per-block weight bytes;
// VGPR_Count=196 proved weights were NEVER register-resident (R3 too: 144
// frag VGPRs vs 128 allocated) — the main GEMM streams weights from L2
// every step (~1-2us/step on the serial critical path).
// R5: (1) fan-in back to 16/32 blocks so weights fit registers (144/136
// VGPRs of frags), (2) amdgpu_waves_per_eu(1,1) to clamp occupancy target
// and unlock the full 512-VGPR budget => compiler keeps frags resident,
// (3) poll by wave0 only (lane-per-slot + __all) then barrier wake — R4's
// all-thread poll storm reverted, (4) keep R4's gate-plane LDS layout
// (bank conflicts halved) and tag-slot publishes.

typedef unsigned short u16;
typedef unsigned int   u32;
typedef unsigned long long u64;
typedef u16   u16x8  __attribute__((ext_vector_type(8)));
typedef __bf16 bf16x8 __attribute__((ext_vector_type(8)));
typedef float f32x4  __attribute__((ext_vector_type(4)));

#define DEV static __device__ __forceinline__

// problem constants
#define BT   64
#define TT   800
#define UU   64
#define HH   512
#define SENT 60
#define NG   2048
#define MOUT 121
#define K1P 576    // X1 = [h1:512][strk:3][w:60][pad:1]
#define K2P 1088   // X2 = [h1:512][h2:512][strk:3][w:60][pad:1]
#define KMD 1024   // Xm = [h1:512][h2:512]
#define KSW 512

#define NBG 4
#define G1B 16
#define G2B 32
#define MDB 2
#define NBLK (NBG*(G1B+G2B+MDB))   // 200

// workspace layout (bytes)
#define OFF_BAR 0
#define OFF_H1  4096
#define OFF_H2  (OFF_H1 + 4*BT*HH*2)
#define OFF_CM  (OFF_H2 + 4*BT*HH*2)
#define OFF_W1  (OFF_CM + 32768)
#define OFF_W2  (OFF_W1 + NG*K1P*2)
#define OFF_WSW (OFF_W2 + NG*K2P*2)
#define OFF_WMD (OFF_WSW + 32*KSW*2)
#define OFF_B1  (OFF_WMD + 128*KMD*2)
#define OFF_B2  (OFF_B1 + NG*4)
#define OFF_BSW (OFF_B2 + NG*4)
#define OFF_BMD (OFF_BSW + 256)
#define WS_NEED (OFF_BMD + 512)
#define ZERO_BYTES OFF_CM   // slots + h1/h2 rings

// output offsets (floats)
#define OW_EOS 0
#define OW_W   (BT*TT)
#define OW_MU1 (OW_W   + BT*TT*20)
#define OW_MU2 (OW_MU1 + BT*TT*20)
#define OW_S1  (OW_MU2 + BT*TT*20)
#define OW_S2  (OW_S1  + BT*TT*20)
#define OW_RHO (OW_S2  + BT*TT*20)

DEV u16 f2bf(float f){
  u32 u = __builtin_bit_cast(u32, f);
  u = (u + 0x7FFFu + ((u >> 16) & 1u)) >> 16;
  return (u16)u;
}
DEV bf16x8 ld8(const u16* p){ return __builtin_bit_cast(bf16x8, *(const u16x8*)p); }
DEV f32x4 mfma16(bf16x8 a, bf16x8 b, f32x4 c){
  return __builtin_amdgcn_mfma_f32_16x16x32_bf16(a, b, c, 0, 0, 0);
}
DEV float sig_(float x){ return 1.f/(1.f + __expf(-x)); }
DEV float tanh_(float x){
  float ax = fabsf(x);
  float e  = __expf(-2.f*ax);
  float t2 = (1.f - e)/(1.f + e);
  return x < 0.f ? -t2 : t2;
}

// ---- L3-coherent (device-scope) memory helpers ----
DEV void ld_tile4(const u16* p, u16x8& a0, u16x8& a1, u16x8& a2, u16x8& a3){
  asm volatile(
    "global_load_dwordx4 %0, %4, off sc0 sc1\n\t"
    "global_load_dwordx4 %1, %4, off offset:256 sc0 sc1\n\t"
    "global_load_dwordx4 %2, %4, off offset:512 sc0 sc1\n\t"
    "global_load_dwordx4 %3, %4, off offset:768 sc0 sc1\n\t"
    "s_waitcnt vmcnt(0)"
    : "=&v"(a0), "=&v"(a1), "=&v"(a2), "=&v"(a3)
    : "v"(p) : "memory");
}
DEV void ld_tile8(const u16* p1, const u16* p2,
                  u16x8& a0,u16x8& a1,u16x8& a2,u16x8& a3,
                  u16x8& b0,u16x8& b1,u16x8& b2,u16x8& b3){
  asm volatile(
    "global_load_dwordx4 %0, %8, off sc0 sc1\n\t"
    "global_load_dwordx4 %1, %8, off offset:256 sc0 sc1\n\t"
    "global_load_dwordx4 %2, %8, off offset:512 sc0 sc1\n\t"
    "global_load_dwordx4 %3, %8, off offset:768 sc0 sc1\n\t"
    "global_load_dwordx4 %4, %9, off sc0 sc1\n\t"
    "global_load_dwordx4 %5, %9, off offset:256 sc0 sc1\n\t"
    "global_load_dwordx4 %6, %9, off offset:512 sc0 sc1\n\t"
    "global_load_dwordx4 %7, %9, off offset:768 sc0 sc1\n\t"
    "s_waitcnt vmcnt(0)"
    : "=&v"(a0),"=&v"(a1),"=&v"(a2),"=&v"(a3),
      "=&v"(b0),"=&v"(b1),"=&v"(b2),"=&v"(b3)
    : "v"(p1), "v"(p2) : "memory");
}
DEV void st_short_sc(u16* p, u32 v){
  asm volatile("global_store_short %0, %1, off sc0 sc1" :: "v"(p), "v"(v) : "memory");
}
DEV void vmwait0(){ asm volatile("s_waitcnt vmcnt(0)" ::: "memory"); }

// tag-slot barrier: per group, 64 u32 slots at bar+bg*64.
//   [0..15] role0 blocks, [16..47] role1 blocks, [48..49] role2 blocks.
// Producer stores step+1 (monotone, never reset). ONLY WAVE 0 polls: one
// lane-indexed sc0sc1 load over the slots + __all() ballot; other waves
// wait at the following __syncthreads.
DEV void poll_slots(const u32* slots, int T0, int T1, int T2){
  if (T0 <= 0 && T1 <= 0 && T2 <= 0) return;
  const int lane = threadIdx.x & 63;
  int thr;
  if (lane < 16)      thr = T0;
  else if (lane < 48) thr = T1;
  else if (lane < 50) thr = T2;
  else                thr = (int)0x80000000;   // always passes
  const u32* p = slots + (lane < 50 ? lane : 63);
  for(;;){
    u32 v;
    asm volatile("global_load_dword %0, %1, off sc0 sc1\n\ts_waitcnt vmcnt(0)"
      : "=&v"(v) : "v"(p) : "memory");
    if (__all((int)v >= thr)) return;
    __builtin_amdgcn_s_sleep(1);
  }
}
DEV void publish(u32* p, int v){
  asm volatile("global_store_dword %0, %1, off sc0 sc1" :: "v"(p), "v"((u32)v) : "memory");
}

// ---------------- weight/bias/mask pre-pack (unchanged) ----------
__global__ __launch_bounds__(256) void pack_kernel(
    const float* __restrict__ Wih1, const float* __restrict__ Whh1,
    const float* __restrict__ bih1, const float* __restrict__ bhh1,
    const float* __restrict__ Wih2, const float* __restrict__ Whh2,
    const float* __restrict__ bih2, const float* __restrict__ bhh2,
    const float* __restrict__ Wsw,  const float* __restrict__ bsw,
    const float* __restrict__ Wmdn, const float* __restrict__ bmdn,
    const float* __restrict__ onehots, char* __restrict__ ws)
{
  u16* Wp1  = (u16*)(ws + OFF_W1);
  u16* Wp2  = (u16*)(ws + OFF_W2);
  u16* Wswp = (u16*)(ws + OFF_WSW);
  u16* Wmdp = (u16*)(ws + OFF_WMD);
  float* b1p  = (float*)(ws + OFF_B1);
  float* b2p  = (float*)(ws + OFF_B2);
  float* bswp = (float*)(ws + OFF_BSW);
  float* bmdp = (float*)(ws + OFF_BMD);
  u64* cmask = (u64*)(ws + OFF_CM);

  const int SA = NG*K1P, SB = NG*K2P, SC = 32*KSW, SD = 128*KMD;
  const int SE = NG + NG + 32 + 128, SF = BT*SENT;
  const int total = SA+SB+SC+SD+SE+SF;
  for (int i = blockIdx.x*blockDim.x + threadIdx.x; i < total; i += gridDim.x*blockDim.x){
    if (i < SA){
      const int n = i / K1P, k = i - n*K1P;
      const int r = (n&3)*HH + (n>>2);
      float f;
      if (k < 512)      f = Whh1[r*HH + k];
      else if (k < 515) f = Wih1[r*63 + (k-512)];
      else if (k < 575) f = Wih1[r*63 + 3 + (k-515)];
      else              f = 0.f;
      Wp1[i] = f2bf(f);
    } else if (i < SA+SB){
      const int j = i - SA;
      const int n = j / K2P, k = j - n*K2P;
      const int r = (n&3)*HH + (n>>2);
      float f;
      if (k < 512)       f = Wih2[r*575 + 3 + k];
      else if (k < 1024) f = Whh2[r*HH + (k-512)];
      else if (k < 1027) f = Wih2[r*575 + (k-1024)];
      else if (k < 1087) f = Wih2[r*575 + 515 + (k-1027)];
      else               f = 0.f;
      Wp2[j] = f2bf(f);
    } else if (i < SA+SB+SC){
      const int j = i - SA - SB;
      const int n = j >> 9, k = j & 511;
      Wswp[j] = f2bf(n < 30 ? Wsw[n*KSW + k] : 0.f);
    } else if (i < SA+SB+SC+SD){
      const int j = i - SA - SB - SC;
      const int n = j >> 10, k = j & 1023;
      float f = 0.f;
      if (n < MOUT) f = (k < 512) ? Wmdn[n*1536 + k]
                                  : (Wmdn[n*1536 + 512 + (k-512)] + Wmdn[n*1536 + 1024 + (k-512)]);
      Wmdp[j] = f2bf(f);
    } else if (i < SA+SB+SC+SD+SE){
      int j = i - SA - SB - SC - SD;
      if (j < NG){ const int r=(j&3)*HH+(j>>2); b1p[j] = bih1[r] + bhh1[r]; }
      else if ((j -= NG) < NG){ const int r=(j&3)*HH+(j>>2); b2p[j] = bih2[r] + bhh2[r]; }
      else if ((j -= NG) < 32){ bswp[j] = (j < 30) ? bsw[j] : 0.f; }
      else { j -= 32; bmdp[j] = (j < MOUT) ? bmdn[j] : 0.f; }
    } else {
      const int j = i - SA - SB - SC - SD - SE;
      const int b = j / SENT, c = j - b*SENT;
      const float* oh = onehots + b*UU*SENT + c;
      u64 m = 0;
#pragma unroll 1
      for (int u = 0; u < UU; ++u) if (oh[u*SENT] > 0.5f) m |= (1ull << u);
      cmask[j] = m;
    }
  }
}

// ---------------- LDS layouts ----------------
// gates planes: [4 gates][16 rows][C+1 cols] — conflict-free gate reads,
// ~2-way writes. gates unioned with pp/phi (disjoint lifetimes).
struct G1S {
  float c[512]; float kk[160];
  u16   X1[16*584];
  union { float gates[4*16*33]; struct { float pp[1024]; float phi[1024]; } a; } u;
  float aa[160], bb[160];
  float smv[1024];
  u64   cm[960];
};
struct G2S {
  float c[256]; float kk[160];
  u16   X2[16*1096];
  union { float gates[4*16*17]; struct { float pp[1024]; float phi[1024]; } a; } u;
  float aa[160], bb[160];
  float smv[1024];
  u64   cm[960];
};
struct MDS { u16 X[16*1032]; float par[16*68]; };
union alignas(16) BigU { G1S g1; G2S g2; MDS md; };

struct WswF { bf16x8 f[8]; };   // by-value => stays in VGPRs after inlining

// attention for step (tw-1): p = h1 @ Wsw^T from staged X (cols 0..511),
// kappa accumulates in kk (private per-block), writes bf16 w directly into
// the X tile tail at tailoff. tw==0 => copy wprev into tail.
DEV void attn_tail(int tw, int bg, u16* X, int xstride, int tailoff,
                   float* pp, float* aa, float* bb, float* kk, float* phi,
                   const float* smv, const u64* cmL, WswF wf,
                   float bswa, float bswb, float bswk,
                   const float* __restrict__ wprev)
{
  const int tid = threadIdx.x;
  if (tw == 0){
    for (int i = tid; i < 16*SENT; i += 256){
      const int b = i / SENT, c = i - b*SENT;
      X[b*xstride + tailoff + c] = f2bf(wprev[(bg*16 + b)*SENT + c]);
    }
    return;
  }
  const int wave = tid >> 6, lane = tid & 63;
  const int quad = lane >> 4, l15 = lane & 15;
  {
    f32x4 acc = {0.f,0.f,0.f,0.f};
    const u16* ap = X + l15*xstride + quad*8 + (wave>>1)*256;
#pragma unroll
    for (int j = 0; j < 8; ++j) acc = mfma16(ld8(ap + j*32), wf.f[j], acc);
    float* dst = pp + (wave>>1)*512;
    const int n = (wave&1)*16 + l15;
#pragma unroll
    for (int r = 0; r < 4; ++r) dst[(quad*4 + r)*32 + n] = acc[r];
  }
  __syncthreads();
  if (tid < 160){
    const int b = tid/10, j = tid - b*10;
    aa[tid] = __expf(pp[b*32 + j]      + pp[512 + b*32 + j]      + bswa);
    bb[tid] = __expf(pp[b*32 + 10 + j] + pp[512 + b*32 + 10 + j] + bswb);
    kk[tid] += __expf(pp[b*32 + 20 + j] + pp[512 + b*32 + 20 + j] + bswk);
  }
  __syncthreads();
  for (int i = tid; i < 1024; i += 256){
    const int b = i >> 6, u = i & 63;
    const float uf = (float)u;
    float acc = 0.f;
#pragma unroll
    for (int j = 0; j < 10; ++j){
      float d = kk[b*10 + j] - uf;
      acc = fmaf(aa[b*10 + j], __expf(-bb[b*10 + j]*d*d), acc);
    }
    phi[i] = acc * smv[i];
  }
  __syncthreads();
  for (int i = tid; i < 16*SENT; i += 256){
    const int b = i / SENT, c = i - b*SENT;
    u64 m = cmL[i];
    float acc = 0.f;
    while (m){ const int u = __builtin_ctzll(m); m &= m - 1; acc += phi[b*64 + u]; }
    X[b*xstride + tailoff + c] = f2bf(acc);
  }
}

// ---------------- main persistent kernel ----------------
__global__ __attribute__((amdgpu_waves_per_eu(1,1))) __launch_bounds__(256)
void rnn_main(
    const float* __restrict__ strks, const float* __restrict__ sm,
    const float* __restrict__ wprev, char* __restrict__ ws,
    float* __restrict__ out)
{
  u32* bar   = (u32*)(ws + OFF_BAR);
  u16* h1pub = (u16*)(ws + OFF_H1);
  u16* h2pub = (u16*)(ws + OFF_H2);
  const u64* cmask = (const u64*)(ws + OFF_CM);
  const u16* Wp1  = (const u16*)(ws + OFF_W1);
  const u16* Wp2  = (const u16*)(ws + OFF_W2);
  const u16* Wswp = (const u16*)(ws + OFF_WSW);
  const u16* Wmdp = (const u16*)(ws + OFF_WMD);
  const float* b1p  = (const float*)(ws + OFF_B1);
  const float* b2p  = (const float*)(ws + OFF_B2);
  const float* bswp = (const float*)(ws + OFF_BSW);
  const float* bmdp = (const float*)(ws + OFF_BMD);

  __shared__ BigU S;

  const int bid = blockIdx.x, tid = threadIdx.x;
  const int wave = tid >> 6, lane = tid & 63;
  const int quad = lane >> 4, l15 = lane & 15;
  const int sb = tid >> 4, sl = tid & 15;

  if (bid < NBG*G1B){
    // ===== role 0: LSTM1 step t; 16 blocks/group, 128 gate cols each =====
    const int bg = bid >> 4, s = bid & 15;
    u32* slots = bar + bg*64;
    bf16x8 w1r[36];
    const int n0 = s*128 + wave*32 + l15, n1 = n0 + 16;
#pragma unroll
    for (int kt = 0; kt < 18; ++kt){
      w1r[2*kt]   = ld8(Wp1 + n0*K1P + quad*8 + kt*32);
      w1r[2*kt+1] = ld8(Wp1 + n1*K1P + quad*8 + kt*32);
    }
    WswF wf;
    { const int nsw = (wave&1)*16 + l15, k0 = (wave>>1)*8;
#pragma unroll
      for (int j = 0; j < 8; ++j) wf.f[j] = ld8(Wswp + nsw*KSW + quad*8 + (k0+j)*32);
    }
    const float bias0 = b1p[n0], bias1 = b1p[n1];
    float bswa = 0.f, bswb = 0.f, bswk = 0.f;
    if (tid < 160){ const int j = tid % 10; bswa = bswp[j]; bswb = bswp[10+j]; bswk = bswp[20+j]; }
    for (int i = tid; i < 512; i += 256) S.g1.c[i] = 0.f;
    if (tid < 160) S.g1.kk[tid] = 0.f;
    for (int i = tid; i < 1024; i += 256) S.g1.smv[i] = sm[(bg*16 + (i>>6))*UU + (i&63)];
    for (int i = tid; i < 960;  i += 256) S.g1.cm[i]  = cmask[(bg*16 + i/60)*SENT + i%60];
    if (sl == 0) S.g1.X1[sb*584 + 575] = 0;
    __syncthreads();

    for (int t = 0; t < TT; ++t){
      float sv = (sl < 3) ? strks[((bg*16 + sb)*TT + t)*3 + sl] : 0.f;
      if (wave == 0) poll_slots(slots, t, t-3, t-3);
      __syncthreads();
      const u16* h1prev = h1pub + ((t+3)&3)*(BT*HH);
      {
        u16x8 a0,a1,a2,a3;
        ld_tile4(h1prev + (bg*16 + sb)*HH + sl*8, a0,a1,a2,a3);
        u16x8* xr = (u16x8*)(S.g1.X1 + sb*584);
        xr[sl] = a0; xr[sl+16] = a1; xr[sl+32] = a2; xr[sl+48] = a3;
        if (sl < 3) S.g1.X1[sb*584 + 512 + sl] = f2bf(sv);
      }
      __syncthreads();
      attn_tail(t, bg, S.g1.X1, 584, 515, S.g1.u.a.pp, S.g1.aa, S.g1.bb, S.g1.kk,
                S.g1.u.a.phi, S.g1.smv, S.g1.cm, wf, bswa, bswb, bswk, wprev);
      __syncthreads();
      f32x4 acc0 = {0.f,0.f,0.f,0.f}, acc1 = {0.f,0.f,0.f,0.f};
      const u16* ap = S.g1.X1 + l15*584 + quad*8;
#pragma unroll
      for (int kt = 0; kt < 18; ++kt){
        bf16x8 av = ld8(ap + kt*32);
        acc0 = mfma16(av, w1r[2*kt],   acc0);
        acc1 = mfma16(av, w1r[2*kt+1], acc1);
      }
      {
        const int gpl = l15 & 3, cbase = wave*8 + (l15 >> 2);
#pragma unroll
        for (int r = 0; r < 4; ++r){
          float* gp = S.g1.u.gates + gpl*528 + (quad*4 + r)*33 + cbase;
          gp[0] = acc0[r] + bias0;
          gp[4] = acc1[r] + bias1;
        }
      }
      __syncthreads();
      u16* h1cur = h1pub + (t&3)*(BT*HH);
      for (int i = tid; i < 512; i += 256){
        const int row = i >> 5, col = i & 31;
        const float* gb = S.g1.u.gates + row*33 + col;
        const float vi = gb[0], vf = gb[528], vg = gb[1056], vo = gb[1584];
        float c = sig_(vf)*S.g1.c[i] + sig_(vi)*tanh_(vg);
        S.g1.c[i] = c;
        st_short_sc(h1cur + (bg*16 + row)*HH + s*32 + col, (u32)f2bf(sig_(vo)*tanh_(c)));
      }
      vmwait0();
      __syncthreads();
      if (tid == 0) publish(slots + s, t+1);
    }
  }
  else if (bid < NBG*(G1B+G2B)){
    // ===== role 1: LSTM2 step te; 32 blocks/group, 64 gate cols each =====
    const int b2 = bid - NBG*G1B, bg = b2 >> 5, s = b2 & 31;
    u32* slots = bar + bg*64;
    bf16x8 w2r[34];
    const int n0 = s*64 + wave*16 + l15;
#pragma unroll
    for (int kt = 0; kt < 34; ++kt) w2r[kt] = ld8(Wp2 + n0*K2P + quad*8 + kt*32);
    WswF wf;
    { const int nsw = (wave&1)*16 + l15, k0 = (wave>>1)*8;
#pragma unroll
      for (int j = 0; j < 8; ++j) wf.f[j] = ld8(Wswp + nsw*KSW + quad*8 + (k0+j)*32);
    }
    const float bias0 = b2p[n0];
    float bswa = 0.f, bswb = 0.f, bswk = 0.f;
    if (tid < 160){ const int j = tid % 10; bswa = bswp[j]; bswb = bswp[10+j]; bswk = bswp[20+j]; }
    if (tid < 256) S.g2.c[tid & 255] = 0.f;
    for (int i = tid; i < 256; i += 256) S.g2.c[i] = 0.f;
    if (tid < 160) S.g2.kk[tid] = 0.f;
    for (int i = tid; i < 1024; i += 256) S.g2.smv[i] = sm[(bg*16 + (i>>6))*UU + (i&63)];
    for (int i = tid; i < 960;  i += 256) S.g2.cm[i]  = cmask[(bg*16 + i/60)*SENT + i%60];
    if (sl == 0) S.g2.X2[sb*1096 + 1087] = 0;
    __syncthreads();

    for (int te = 0; te < TT; ++te){
      float sv = (sl < 3) ? strks[((bg*16 + sb)*TT + te)*3 + sl] : 0.f;
      if (wave == 0) poll_slots(slots, te+1, te, te-3);
      __syncthreads();
      const u16* h1te = h1pub + (te&3)*(BT*HH);
      const u16* h2pv = h2pub + ((te+3)&3)*(BT*HH);
      {
        u16x8 a0,a1,a2,a3,b0,b1,b2v,b3;
        ld_tile8(h1te + (bg*16 + sb)*HH + sl*8, h2pv + (bg*16 + sb)*HH + sl*8,
                 a0,a1,a2,a3, b0,b1,b2v,b3);
        u16x8* xr = (u16x8*)(S.g2.X2 + sb*1096);
        xr[sl] = a0; xr[sl+16] = a1; xr[sl+32] = a2; xr[sl+48] = a3;
        xr[64+sl] = b0; xr[64+sl+16] = b1; xr[64+sl+32] = b2v; xr[64+sl+48] = b3;
        if (sl < 3) S.g2.X2[sb*1096 + 1024 + sl] = f2bf(sv);
      }
      __syncthreads();
      attn_tail(te+1, bg, S.g2.X2, 1096, 1027, S.g2.u.a.pp, S.g2.aa, S.g2.bb, S.g2.kk,
                S.g2.u.a.phi, S.g2.smv, S.g2.cm, wf, bswa, bswb, bswk, wprev);
      __syncthreads();
      f32x4 acc = {0.f,0.f,0.f,0.f};
      const u16* ap = S.g2.X2 + l15*1096 + quad*8;
#pragma unroll
      for (int kt = 0; kt < 34; ++kt) acc = mfma16(ld8(ap + kt*32), w2r[kt], acc);
      {
        const int gpl = l15 & 3, cbase = wave*4 + (l15 >> 2);
#pragma unroll
        for (int r = 0; r < 4; ++r){
          float* gp = S.g2.u.gates + gpl*272 + (quad*4 + r)*17 + cbase;
          gp[0] = acc[r] + bias0;
        }
      }
      __syncthreads();
      u16* h2cur = h2pub + (te&3)*(BT*HH);
      {
        const int row = tid >> 4, col = tid & 15;
        const float* gb = S.g2.u.gates + row*17 + col;
        const float vi = gb[0], vf = gb[272], vg = gb[544], vo = gb[816];
        float c = sig_(vf)*S.g2.c[tid] + sig_(vi)*tanh_(vg);
        S.g2.c[tid] = c;
        st_short_sc(h2cur + (bg*16 + row)*HH + s*16 + col, (u32)f2bf(sig_(vo)*tanh_(c)));
      }
      vmwait0();
      __syncthreads();
      if (tid == 0) publish(slots + 16 + s, te+1);
    }
  }
  else {
    // ===== role 2: MDN head, step te (signals after staging) =====
    const int b2 = bid - NBG*(G1B+G2B), bg = b2 >> 1, s = b2 & 1;
    u32* slots = bar + bg*64;
    bf16x8 wmr[32];
    const int n0 = s*64 + wave*16 + l15;
#pragma unroll
    for (int kt = 0; kt < 32; ++kt) wmr[kt] = ld8(Wmdp + n0*KMD + quad*8 + kt*32);
    const float bias0 = bmdp[n0];
    __syncthreads();

    for (int te = 0; te < TT; ++te){
      if (wave == 0) poll_slots(slots, 0, te+1, 0);
      __syncthreads();
      const u16* h1te = h1pub + (te&3)*(BT*HH);
      const u16* h2te = h2pub + (te&3)*(BT*HH);
      {
        u16x8 a0,a1,a2,a3,b0,b1,b2v,b3;
        ld_tile8(h1te + (bg*16 + sb)*HH + sl*8, h2te + (bg*16 + sb)*HH + sl*8,
                 a0,a1,a2,a3, b0,b1,b2v,b3);
        u16x8* xr = (u16x8*)(S.md.X + sb*1032);
        xr[sl] = a0; xr[sl+16] = a1; xr[sl+32] = a2; xr[sl+48] = a3;
        xr[64+sl] = b0; xr[64+sl+16] = b1; xr[64+sl+32] = b2v; xr[64+sl+48] = b3;
      }
      __syncthreads();
      if (tid == 0) publish(slots + 48 + s, te+1);   // ring reads done
      f32x4 acc = {0.f,0.f,0.f,0.f};
      const u16* ap = S.md.X + l15*1032 + quad*8;
#pragma unroll
      for (int kt = 0; kt < 32; ++kt) acc = mfma16(ld8(ap + kt*32), wmr[kt], acc);
#pragma unroll
      for (int r = 0; r < 4; ++r)
        S.md.par[(quad*4 + r)*68 + wave*16 + l15] = acc[r] + bias0;
      __syncthreads();
      for (int i = tid; i < 1024; i += 256){
        const int b = i >> 6, lc = i & 63, gc = s*64 + lc;
        const int bt = (bg*16 + b)*TT + te;
        const float v = S.md.par[b*68 + lc];
        if (gc >= 20 && gc < 40)        out[OW_MU1 + bt*20 + (gc-20)]  = v;
        else if (gc >= 40 && gc < 60)   out[OW_MU2 + bt*20 + (gc-40)]  = v;
        else if (gc >= 60 && gc < 80)   out[OW_S1  + bt*20 + (gc-60)]  = __expf(v);
        else if (gc >= 80 && gc < 100)  out[OW_S2  + bt*20 + (gc-80)]  = __expf(v);
        else if (gc >= 100 && gc < 120) out[OW_RHO + bt*20 + (gc-100)] = tanh_(v);
        else if (gc == 120)             out[OW_EOS + bt]               = sig_(v);
      }
      if (s == 0 && tid < 16){
        const int b = tid;
        const int bt = (bg*16 + b)*TT + te;
        float mx = -1e30f;
        for (int c = 0; c < 20; ++c) mx = fmaxf(mx, S.md.par[b*68 + c]);
        float sum = 0.f;
        for (int c = 0; c < 20; ++c) sum += __expf(S.md.par[b*68 + c] - mx);
        const float inv = 1.f/sum;
        for (int c = 0; c < 20; ++c)
          out[OW_W + bt*20 + c] = __expf(S.md.par[b*68 + c] - mx)*inv;
      }
    }
  }
}

extern "C" void kernel_launch(void* const* d_in, const int* in_sizes, int n_in,
                              void* d_out, int out_size, void* d_ws, size_t ws_size,
                              hipStream_t stream)
{
  const float* strks   = (const float*)d_in[0];
  const float* sentsm  = (const float*)d_in[3];
  const float* onehots = (const float*)d_in[4];
  const float* wprev   = (const float*)d_in[5];
  const float* Wih1 = (const float*)d_in[6];
  const float* Whh1 = (const float*)d_in[7];
  const float* bih1 = (const float*)d_in[8];
  const float* bhh1 = (const float*)d_in[9];
  const float* Wih2 = (const float*)d_in[10];
  const float* Whh2 = (const float*)d_in[11];
  const float* bih2 = (const float*)d_in[12];
  const float* bhh2 = (const float*)d_in[13];
  const float* Wsw  = (const float*)d_in[14];
  const float* bsw  = (const float*)d_in[15];
  const float* Wmdn = (const float*)d_in[16];
  const float* bmdn = (const float*)d_in[17];
  (void)in_sizes; (void)n_in; (void)out_size;

  if (ws_size < (size_t)WS_NEED) return;

  hipMemsetAsync(d_ws, 0, ZERO_BYTES, stream);
  pack_kernel<<<2048, 256, 0, stream>>>(Wih1, Whh1, bih1, bhh1, Wih2, Whh2, bih2, bhh2,
                                        Wsw, bsw, Wmdn, bmdn, onehots, (char*)d_ws);
  rnn_main<<<NBLK, 256, 0, stream>>>(strks, sentsm, wprev, (char*)d_ws, (float*)d_out);
}

// Round 3
// 5748.076 us; speedup vs baseline: 1.1593x; 1.0169x over previous
//
#include <hip/hip_runtime.h>

// Handwriting synthesis RNN — persistent fused kernel, R6.
// R6 vs R5 post-mortem: occupancy hints ((256,1), waves_per_eu(1,1)) never
// move the allocator past ~132 VGPRs, so the ~144-VGPR weight fragment sets
// are scratch-spilled and re-read EVERY timestep (illegal to remat from L2
// across the asm "memory" clobbers => must be scratch). That streaming, plus
// the resulting L2 churn (FETCH 537KB/step ~ per-XCD weight set ~ L2 size),
// is the straggler driver.
// R6: (1) pin all weight fragments into AGPRs via empty asm "+a" constraints
// — the AGPR side of the unified file is empty, mfma builtins read AV class
// directly, so weights become truly resident; (2) pack ring h-stores into
// dword stores (halves fabric transactions on the publish path). Structure,
// sync, LDS layouts unchanged from R5.

typedef unsigned short u16;
typedef unsigned int   u32;
typedef unsigned long long u64;
typedef u16   u16x8  __attribute__((ext_vector_type(8)));
typedef u32   u32x4  __attribute__((ext_vector_type(4)));
typedef __bf16 bf16x8 __attribute__((ext_vector_type(8)));
typedef float f32x4  __attribute__((ext_vector_type(4)));

#define DEV static __device__ __forceinline__

// problem constants
#define BT   64
#define TT   800
#define UU   64
#define HH   512
#define SENT 60
#define NG   2048
#define MOUT 121
#define K1P 576    // X1 = [h1:512][strk:3][w:60][pad:1]
#define K2P 1088   // X2 = [h1:512][h2:512][strk:3][w:60][pad:1]
#define KMD 1024   // Xm = [h1:512][h2:512]
#define KSW 512

#define NBG 4
#define G1B 16
#define G2B 32
#define MDB 2
#define NBLK (NBG*(G1B+G2B+MDB))   // 200

// workspace layout (bytes)
#define OFF_BAR 0
#define OFF_H1  4096
#define OFF_H2  (OFF_H1 + 4*BT*HH*2)
#define OFF_CM  (OFF_H2 + 4*BT*HH*2)
#define OFF_W1  (OFF_CM + 32768)
#define OFF_W2  (OFF_W1 + NG*K1P*2)
#define OFF_WSW (OFF_W2 + NG*K2P*2)
#define OFF_WMD (OFF_WSW + 32*KSW*2)
#define OFF_B1  (OFF_WMD + 128*KMD*2)
#define OFF_B2  (OFF_B1 + NG*4)
#define OFF_BSW (OFF_B2 + NG*4)
#define OFF_BMD (OFF_BSW + 256)
#define WS_NEED (OFF_BMD + 512)
#define ZERO_BYTES OFF_CM   // slots + h1/h2 rings

// output offsets (floats)
#define OW_EOS 0
#define OW_W   (BT*TT)
#define OW_MU1 (OW_W   + BT*TT*20)
#define OW_MU2 (OW_MU1 + BT*TT*20)
#define OW_S1  (OW_MU2 + BT*TT*20)
#define OW_S2  (OW_S1  + BT*TT*20)
#define OW_RHO (OW_S2  + BT*TT*20)

DEV u16 f2bf(float f){
  u32 u = __builtin_bit_cast(u32, f);
  u = (u + 0x7FFFu + ((u >> 16) & 1u)) >> 16;
  return (u16)u;
}
DEV bf16x8 ld8(const u16* p){ return __builtin_bit_cast(bf16x8, *(const u16x8*)p); }
DEV f32x4 mfma16(bf16x8 a, bf16x8 b, f32x4 c){
  return __builtin_amdgcn_mfma_f32_16x16x32_bf16(a, b, c, 0, 0, 0);
}
DEV float sig_(float x){ return 1.f/(1.f + __expf(-x)); }
DEV float tanh_(float x){
  float ax = fabsf(x);
  float e  = __expf(-2.f*ax);
  float t2 = (1.f - e)/(1.f + e);
  return x < 0.f ? -t2 : t2;
}

// Pin a bf16x8 fragment's live range into the AGPR class. The empty asm's
// "+a" def forces the value into AGPRs; mfma builtins read AV class on
// gfx950, so the value stays there — truly register-resident weights that
// don't fight for the ~130-VGPR budget.
DEV void pin_agpr(bf16x8& v){
  u32x4 t = __builtin_bit_cast(u32x4, v);
  asm volatile("" : "+a"(t));
  v = __builtin_bit_cast(bf16x8, t);
}

// ---- L3-coherent (device-scope) memory helpers ----
DEV void ld_tile4(const u16* p, u16x8& a0, u16x8& a1, u16x8& a2, u16x8& a3){
  asm volatile(
    "global_load_dwordx4 %0, %4, off sc0 sc1\n\t"
    "global_load_dwordx4 %1, %4, off offset:256 sc0 sc1\n\t"
    "global_load_dwordx4 %2, %4, off offset:512 sc0 sc1\n\t"
    "global_load_dwordx4 %3, %4, off offset:768 sc0 sc1\n\t"
    "s_waitcnt vmcnt(0)"
    : "=&v"(a0), "=&v"(a1), "=&v"(a2), "=&v"(a3)
    : "v"(p) : "memory");
}
DEV void ld_tile8(const u16* p1, const u16* p2,
                  u16x8& a0,u16x8& a1,u16x8& a2,u16x8& a3,
                  u16x8& b0,u16x8& b1,u16x8& b2,u16x8& b3){
  asm volatile(
    "global_load_dwordx4 %0, %8, off sc0 sc1\n\t"
    "global_load_dwordx4 %1, %8, off offset:256 sc0 sc1\n\t"
    "global_load_dwordx4 %2, %8, off offset:512 sc0 sc1\n\t"
    "global_load_dwordx4 %3, %8, off offset:768 sc0 sc1\n\t"
    "global_load_dwordx4 %4, %9, off sc0 sc1\n\t"
    "global_load_dwordx4 %5, %9, off offset:256 sc0 sc1\n\t"
    "global_load_dwordx4 %6, %9, off offset:512 sc0 sc1\n\t"
    "global_load_dwordx4 %7, %9, off offset:768 sc0 sc1\n\t"
    "s_waitcnt vmcnt(0)"
    : "=&v"(a0),"=&v"(a1),"=&v"(a2),"=&v"(a3),
      "=&v"(b0),"=&v"(b1),"=&v"(b2),"=&v"(b3)
    : "v"(p1), "v"(p2) : "memory");
}
DEV void st_dword_sc(u32* p, u32 v){
  asm volatile("global_store_dword %0, %1, off sc0 sc1" :: "v"(p), "v"(v) : "memory");
}
DEV void vmwait0(){ asm volatile("s_waitcnt vmcnt(0)" ::: "memory"); }

// tag-slot barrier: per group, 64 u32 slots at bar+bg*64.
//   [0..15] role0 blocks, [16..47] role1 blocks, [48..49] role2 blocks.
// Producer stores step+1 (monotone, never reset). ONLY WAVE 0 polls: one
// lane-indexed sc0sc1 load over the slots + __all() ballot; other waves
// wait at the following __syncthreads.
DEV void poll_slots(const u32* slots, int T0, int T1, int T2){
  if (T0 <= 0 && T1 <= 0 && T2 <= 0) return;
  const int lane = threadIdx.x & 63;
  int thr;
  if (lane < 16)      thr = T0;
  else if (lane < 48) thr = T1;
  else if (lane < 50) thr = T2;
  else                thr = (int)0x80000000;   // always passes
  const u32* p = slots + (lane < 50 ? lane : 63);
  for(;;){
    u32 v;
    asm volatile("global_load_dword %0, %1, off sc0 sc1\n\ts_waitcnt vmcnt(0)"
      : "=&v"(v) : "v"(p) : "memory");
    if (__all((int)v >= thr)) return;
    __builtin_amdgcn_s_sleep(1);
  }
}
DEV void publish(u32* p, int v){
  asm volatile("global_store_dword %0, %1, off sc0 sc1" :: "v"(p), "v"((u32)v) : "memory");
}

// ---------------- weight/bias/mask pre-pack (unchanged) ----------
__global__ __launch_bounds__(256) void pack_kernel(
    const float* __restrict__ Wih1, const float* __restrict__ Whh1,
    const float* __restrict__ bih1, const float* __restrict__ bhh1,
    const float* __restrict__ Wih2, const float* __restrict__ Whh2,
    const float* __restrict__ bih2, const float* __restrict__ bhh2,
    const float* __restrict__ Wsw,  const float* __restrict__ bsw,
    const float* __restrict__ Wmdn, const float* __restrict__ bmdn,
    const float* __restrict__ onehots, char* __restrict__ ws)
{
  u16* Wp1  = (u16*)(ws + OFF_W1);
  u16* Wp2  = (u16*)(ws + OFF_W2);
  u16* Wswp = (u16*)(ws + OFF_WSW);
  u16* Wmdp = (u16*)(ws + OFF_WMD);
  float* b1p  = (float*)(ws + OFF_B1);
  float* b2p  = (float*)(ws + OFF_B2);
  float* bswp = (float*)(ws + OFF_BSW);
  float* bmdp = (float*)(ws + OFF_BMD);
  u64* cmask = (u64*)(ws + OFF_CM);

  const int SA = NG*K1P, SB = NG*K2P, SC = 32*KSW, SD = 128*KMD;
  const int SE = NG + NG + 32 + 128, SF = BT*SENT;
  const int total = SA+SB+SC+SD+SE+SF;
  for (int i = blockIdx.x*blockDim.x + threadIdx.x; i < total; i += gridDim.x*blockDim.x){
    if (i < SA){
      const int n = i / K1P, k = i - n*K1P;
      const int r = (n&3)*HH + (n>>2);
      float f;
      if (k < 512)      f = Whh1[r*HH + k];
      else if (k < 515) f = Wih1[r*63 + (k-512)];
      else if (k < 575) f = Wih1[r*63 + 3 + (k-515)];
      else              f = 0.f;
      Wp1[i] = f2bf(f);
    } else if (i < SA+SB){
      const int j = i - SA;
      const int n = j / K2P, k = j - n*K2P;
      const int r = (n&3)*HH + (n>>2);
      float f;
      if (k < 512)       f = Wih2[r*575 + 3 + k];
      else if (k < 1024) f = Whh2[r*HH + (k-512)];
      else if (k < 1027) f = Wih2[r*575 + (k-1024)];
      else if (k < 1087) f = Wih2[r*575 + 515 + (k-1027)];
      else               f = 0.f;
      Wp2[j] = f2bf(f);
    } else if (i < SA+SB+SC){
      const int j = i - SA - SB;
      const int n = j >> 9, k = j & 511;
      Wswp[j] = f2bf(n < 30 ? Wsw[n*KSW + k] : 0.f);
    } else if (i < SA+SB+SC+SD){
      const int j = i - SA - SB - SC;
      const int n = j >> 10, k = j & 1023;
      float f = 0.f;
      if (n < MOUT) f = (k < 512) ? Wmdn[n*1536 + k]
                                  : (Wmdn[n*1536 + 512 + (k-512)] + Wmdn[n*1536 + 1024 + (k-512)]);
      Wmdp[j] = f2bf(f);
    } else if (i < SA+SB+SC+SD+SE){
      int j = i - SA - SB - SC - SD;
      if (j < NG){ const int r=(j&3)*HH+(j>>2); b1p[j] = bih1[r] + bhh1[r]; }
      else if ((j -= NG) < NG){ const int r=(j&3)*HH+(j>>2); b2p[j] = bih2[r] + bhh2[r]; }
      else if ((j -= NG) < 32){ bswp[j] = (j < 30) ? bsw[j] : 0.f; }
      else { j -= 32; bmdp[j] = (j < MOUT) ? bmdn[j] : 0.f; }
    } else {
      const int j = i - SA - SB - SC - SD - SE;
      const int b = j / SENT, c = j - b*SENT;
      const float* oh = onehots + b*UU*SENT + c;
      u64 m = 0;
#pragma unroll 1
      for (int u = 0; u < UU; ++u) if (oh[u*SENT] > 0.5f) m |= (1ull << u);
      cmask[j] = m;
    }
  }
}

// ---------------- LDS layouts ----------------
// gates planes: [4 gates][16 rows][C+1 cols] — conflict-free gate reads,
// ~2-way writes. gates unioned with pp/phi (disjoint lifetimes).
struct G1S {
  float c[512]; float kk[160];
  u16   X1[16*584];
  union { float gates[4*16*33]; struct { float pp[1024]; float phi[1024]; } a; } u;
  float aa[160], bb[160];
  float smv[1024];
  u64   cm[960];
};
struct G2S {
  float c[256]; float kk[160];
  u16   X2[16*1096];
  union { float gates[4*16*17]; struct { float pp[1024]; float phi[1024]; } a; } u;
  float aa[160], bb[160];
  float smv[1024];
  u64   cm[960];
};
struct MDS { u16 X[16*1032]; float par[16*68]; };
union alignas(16) BigU { G1S g1; G2S g2; MDS md; };

struct WswF { bf16x8 f[8]; };

// attention for step (tw-1): p = h1 @ Wsw^T from staged X (cols 0..511),
// kappa accumulates in kk (private per-block), writes bf16 w directly into
// the X tile tail at tailoff. tw==0 => copy wprev into tail.
DEV void attn_tail(int tw, int bg, u16* X, int xstride, int tailoff,
                   float* pp, float* aa, float* bb, float* kk, float* phi,
                   const float* smv, const u64* cmL, WswF wf,
                   float bswa, float bswb, float bswk,
                   const float* __restrict__ wprev)
{
  const int tid = threadIdx.x;
  if (tw == 0){
    for (int i = tid; i < 16*SENT; i += 256){
      const int b = i / SENT, c = i - b*SENT;
      X[b*xstride + tailoff + c] = f2bf(wprev[(bg*16 + b)*SENT + c]);
    }
    return;
  }
  const int wave = tid >> 6, lane = tid & 63;
  const int quad = lane >> 4, l15 = lane & 15;
  {
    f32x4 acc = {0.f,0.f,0.f,0.f};
    const u16* ap = X + l15*xstride + quad*8 + (wave>>1)*256;
#pragma unroll
    for (int j = 0; j < 8; ++j) acc = mfma16(ld8(ap + j*32), wf.f[j], acc);
    float* dst = pp + (wave>>1)*512;
    const int n = (wave&1)*16 + l15;
#pragma unroll
    for (int r = 0; r < 4; ++r) dst[(quad*4 + r)*32 + n] = acc[r];
  }
  __syncthreads();
  if (tid < 160){
    const int b = tid/10, j = tid - b*10;
    aa[tid] = __expf(pp[b*32 + j]      + pp[512 + b*32 + j]      + bswa);
    bb[tid] = __expf(pp[b*32 + 10 + j] + pp[512 + b*32 + 10 + j] + bswb);
    kk[tid] += __expf(pp[b*32 + 20 + j] + pp[512 + b*32 + 20 + j] + bswk);
  }
  __syncthreads();
  for (int i = tid; i < 1024; i += 256){
    const int b = i >> 6, u = i & 63;
    const float uf = (float)u;
    float acc = 0.f;
#pragma unroll
    for (int j = 0; j < 10; ++j){
      float d = kk[b*10 + j] - uf;
      acc = fmaf(aa[b*10 + j], __expf(-bb[b*10 + j]*d*d), acc);
    }
    phi[i] = acc * smv[i];
  }
  __syncthreads();
  for (int i = tid; i < 16*SENT; i += 256){
    const int b = i / SENT, c = i - b*SENT;
    u64 m = cmL[i];
    float acc = 0.f;
    while (m){ const int u = __builtin_ctzll(m); m &= m - 1; acc += phi[b*64 + u]; }
    X[b*xstride + tailoff + c] = f2bf(acc);
  }
}

// ---------------- main persistent kernel ----------------
__global__ __attribute__((amdgpu_waves_per_eu(1,1))) __launch_bounds__(256)
void rnn_main(
    const float* __restrict__ strks, const float* __restrict__ sm,
    const float* __restrict__ wprev, char* __restrict__ ws,
    float* __restrict__ out)
{
  u32* bar   = (u32*)(ws + OFF_BAR);
  u16* h1pub = (u16*)(ws + OFF_H1);
  u16* h2pub = (u16*)(ws + OFF_H2);
  const u64* cmask = (const u64*)(ws + OFF_CM);
  const u16* Wp1  = (const u16*)(ws + OFF_W1);
  const u16* Wp2  = (const u16*)(ws + OFF_W2);
  const u16* Wswp = (const u16*)(ws + OFF_WSW);
  const u16* Wmdp = (const u16*)(ws + OFF_WMD);
  const float* b1p  = (const float*)(ws + OFF_B1);
  const float* b2p  = (const float*)(ws + OFF_B2);
  const float* bswp = (const float*)(ws + OFF_BSW);
  const float* bmdp = (const float*)(ws + OFF_BMD);

  __shared__ BigU S;

  const int bid = blockIdx.x, tid = threadIdx.x;
  const int wave = tid >> 6, lane = tid & 63;
  const int quad = lane >> 4, l15 = lane & 15;
  const int sb = tid >> 4, sl = tid & 15;

  if (bid < NBG*G1B){
    // ===== role 0: LSTM1 step t; 16 blocks/group, 128 gate cols each =====
    const int bg = bid >> 4, s = bid & 15;
    u32* slots = bar + bg*64;
    bf16x8 w1r[36];
    const int n0 = s*128 + wave*32 + l15, n1 = n0 + 16;
#pragma unroll
    for (int kt = 0; kt < 18; ++kt){
      w1r[2*kt]   = ld8(Wp1 + n0*K1P + quad*8 + kt*32);
      w1r[2*kt+1] = ld8(Wp1 + n1*K1P + quad*8 + kt*32);
    }
#pragma unroll
    for (int i = 0; i < 36; ++i) pin_agpr(w1r[i]);
    WswF wf;
    { const int nsw = (wave&1)*16 + l15, k0 = (wave>>1)*8;
#pragma unroll
      for (int j = 0; j < 8; ++j) wf.f[j] = ld8(Wswp + nsw*KSW + quad*8 + (k0+j)*32);
#pragma unroll
      for (int j = 0; j < 8; ++j) pin_agpr(wf.f[j]);
    }
    const float bias0 = b1p[n0], bias1 = b1p[n1];
    float bswa = 0.f, bswb = 0.f, bswk = 0.f;
    if (tid < 160){ const int j = tid % 10; bswa = bswp[j]; bswb = bswp[10+j]; bswk = bswp[20+j]; }
    for (int i = tid; i < 512; i += 256) S.g1.c[i] = 0.f;
    if (tid < 160) S.g1.kk[tid] = 0.f;
    for (int i = tid; i < 1024; i += 256) S.g1.smv[i] = sm[(bg*16 + (i>>6))*UU + (i&63)];
    for (int i = tid; i < 960;  i += 256) S.g1.cm[i]  = cmask[(bg*16 + i/60)*SENT + i%60];
    if (sl == 0) S.g1.X1[sb*584 + 575] = 0;
    __syncthreads();

    for (int t = 0; t < TT; ++t){
      float sv = (sl < 3) ? strks[((bg*16 + sb)*TT + t)*3 + sl] : 0.f;
      if (wave == 0) poll_slots(slots, t, t-3, t-3);
      __syncthreads();
      const u16* h1prev = h1pub + ((t+3)&3)*(BT*HH);
      {
        u16x8 a0,a1,a2,a3;
        ld_tile4(h1prev + (bg*16 + sb)*HH + sl*8, a0,a1,a2,a3);
        u16x8* xr = (u16x8*)(S.g1.X1 + sb*584);
        xr[sl] = a0; xr[sl+16] = a1; xr[sl+32] = a2; xr[sl+48] = a3;
        if (sl < 3) S.g1.X1[sb*584 + 512 + sl] = f2bf(sv);
      }
      __syncthreads();
      attn_tail(t, bg, S.g1.X1, 584, 515, S.g1.u.a.pp, S.g1.aa, S.g1.bb, S.g1.kk,
                S.g1.u.a.phi, S.g1.smv, S.g1.cm, wf, bswa, bswb, bswk, wprev);
      __syncthreads();
      f32x4 acc0 = {0.f,0.f,0.f,0.f}, acc1 = {0.f,0.f,0.f,0.f};
      const u16* ap = S.g1.X1 + l15*584 + quad*8;
#pragma unroll
      for (int kt = 0; kt < 18; ++kt){
        bf16x8 av = ld8(ap + kt*32);
        acc0 = mfma16(av, w1r[2*kt],   acc0);
        acc1 = mfma16(av, w1r[2*kt+1], acc1);
      }
      {
        const int gpl = l15 & 3, cbase = wave*8 + (l15 >> 2);
#pragma unroll
        for (int r = 0; r < 4; ++r){
          float* gp = S.g1.u.gates + gpl*528 + (quad*4 + r)*33 + cbase;
          gp[0] = acc0[r] + bias0;
          gp[4] = acc1[r] + bias1;
        }
      }
      __syncthreads();
      u16* h1cur = h1pub + (t&3)*(BT*HH);
      {
        // 2 adjacent cols per thread -> one dword store
        const int row = tid >> 4, cp = tid & 15;
        const float* gb = S.g1.u.gates + row*33 + 2*cp;
        const int ci = row*32 + 2*cp;
        float c0 = sig_(gb[528])*S.g1.c[ci]   + sig_(gb[0])*tanh_(gb[1056]);
        float c1 = sig_(gb[529])*S.g1.c[ci+1] + sig_(gb[1])*tanh_(gb[1057]);
        S.g1.c[ci] = c0; S.g1.c[ci+1] = c1;
        u32 v = (u32)f2bf(sig_(gb[1584])*tanh_(c0)) |
                ((u32)f2bf(sig_(gb[1585])*tanh_(c1)) << 16);
        st_dword_sc((u32*)(h1cur + (bg*16 + row)*HH + s*32 + 2*cp), v);
      }
      vmwait0();
      __syncthreads();
      if (tid == 0) publish(slots + s, t+1);
    }
  }
  else if (bid < NBG*(G1B+G2B)){
    // ===== role 1: LSTM2 step te; 32 blocks/group, 64 gate cols each =====
    const int b2 = bid - NBG*G1B, bg = b2 >> 5, s = b2 & 31;
    u32* slots = bar + bg*64;
    bf16x8 w2r[34];
    const int n0 = s*64 + wave*16 + l15;
#pragma unroll
    for (int kt = 0; kt < 34; ++kt) w2r[kt] = ld8(Wp2 + n0*K2P + quad*8 + kt*32);
#pragma unroll
    for (int i = 0; i < 34; ++i) pin_agpr(w2r[i]);
    WswF wf;
    { const int nsw = (wave&1)*16 + l15, k0 = (wave>>1)*8;
#pragma unroll
      for (int j = 0; j < 8; ++j) wf.f[j] = ld8(Wswp + nsw*KSW + quad*8 + (k0+j)*32);
#pragma unroll
      for (int j = 0; j < 8; ++j) pin_agpr(wf.f[j]);
    }
    const float bias0 = b2p[n0];
    float bswa = 0.f, bswb = 0.f, bswk = 0.f;
    if (tid < 160){ const int j = tid % 10; bswa = bswp[j]; bswb = bswp[10+j]; bswk = bswp[20+j]; }
    S.g2.c[tid] = 0.f;
    if (tid < 160) S.g2.kk[tid] = 0.f;
    for (int i = tid; i < 1024; i += 256) S.g2.smv[i] = sm[(bg*16 + (i>>6))*UU + (i&63)];
    for (int i = tid; i < 960;  i += 256) S.g2.cm[i]  = cmask[(bg*16 + i/60)*SENT + i%60];
    if (sl == 0) S.g2.X2[sb*1096 + 1087] = 0;
    __syncthreads();

    for (int te = 0; te < TT; ++te){
      float sv = (sl < 3) ? strks[((bg*16 + sb)*TT + te)*3 + sl] : 0.f;
      if (wave == 0) poll_slots(slots, te+1, te, te-3);
      __syncthreads();
      const u16* h1te = h1pub + (te&3)*(BT*HH);
      const u16* h2pv = h2pub + ((te+3)&3)*(BT*HH);
      {
        u16x8 a0,a1,a2,a3,b0,b1,b2v,b3;
        ld_tile8(h1te + (bg*16 + sb)*HH + sl*8, h2pv + (bg*16 + sb)*HH + sl*8,
                 a0,a1,a2,a3, b0,b1,b2v,b3);
        u16x8* xr = (u16x8*)(S.g2.X2 + sb*1096);
        xr[sl] = a0; xr[sl+16] = a1; xr[sl+32] = a2; xr[sl+48] = a3;
        xr[64+sl] = b0; xr[64+sl+16] = b1; xr[64+sl+32] = b2v; xr[64+sl+48] = b3;
        if (sl < 3) S.g2.X2[sb*1096 + 1024 + sl] = f2bf(sv);
      }
      __syncthreads();
      attn_tail(te+1, bg, S.g2.X2, 1096, 1027, S.g2.u.a.pp, S.g2.aa, S.g2.bb, S.g2.kk,
                S.g2.u.a.phi, S.g2.smv, S.g2.cm, wf, bswa, bswb, bswk, wprev);
      __syncthreads();
      f32x4 acc = {0.f,0.f,0.f,0.f};
      const u16* ap = S.g2.X2 + l15*1096 + quad*8;
#pragma unroll
      for (int kt = 0; kt < 34; ++kt) acc = mfma16(ld8(ap + kt*32), w2r[kt], acc);
      {
        const int gpl = l15 & 3, cbase = wave*4 + (l15 >> 2);
#pragma unroll
        for (int r = 0; r < 4; ++r){
          float* gp = S.g2.u.gates + gpl*272 + (quad*4 + r)*17 + cbase;
          gp[0] = acc[r] + bias0;
        }
      }
      __syncthreads();
      u16* h2cur = h2pub + (te&3)*(BT*HH);
      if (tid < 128){
        const int row = tid >> 3, cp = tid & 7;
        const float* gb = S.g2.u.gates + row*17 + 2*cp;
        const int ci = row*16 + 2*cp;
        float c0 = sig_(gb[272])*S.g2.c[ci]   + sig_(gb[0])*tanh_(gb[544]);
        float c1 = sig_(gb[273])*S.g2.c[ci+1] + sig_(gb[1])*tanh_(gb[545]);
        S.g2.c[ci] = c0; S.g2.c[ci+1] = c1;
        u32 v = (u32)f2bf(sig_(gb[816])*tanh_(c0)) |
                ((u32)f2bf(sig_(gb[817])*tanh_(c1)) << 16);
        st_dword_sc((u32*)(h2cur + (bg*16 + row)*HH + s*16 + 2*cp), v);
      }
      vmwait0();
      __syncthreads();
      if (tid == 0) publish(slots + 16 + s, te+1);
    }
  }
  else {
    // ===== role 2: MDN head, step te (signals after staging) =====
    const int b2 = bid - NBG*(G1B+G2B), bg = b2 >> 1, s = b2 & 1;
    u32* slots = bar + bg*64;
    bf16x8 wmr[32];
    const int n0 = s*64 + wave*16 + l15;
#pragma unroll
    for (int kt = 0; kt < 32; ++kt) wmr[kt] = ld8(Wmdp + n0*KMD + quad*8 + kt*32);
#pragma unroll
    for (int i = 0; i < 32; ++i) pin_agpr(wmr[i]);
    const float bias0 = bmdp[n0];
    __syncthreads();

    for (int te = 0; te < TT; ++te){
      if (wave == 0) poll_slots(slots, 0, te+1, 0);
      __syncthreads();
      const u16* h1te = h1pub + (te&3)*(BT*HH);
      const u16* h2te = h2pub + (te&3)*(BT*HH);
      {
        u16x8 a0,a1,a2,a3,b0,b1,b2v,b3;
        ld_tile8(h1te + (bg*16 + sb)*HH + sl*8, h2te + (bg*16 + sb)*HH + sl*8,
                 a0,a1,a2,a3, b0,b1,b2v,b3);
        u16x8* xr = (u16x8*)(S.md.X + sb*1032);
        xr[sl] = a0; xr[sl+16] = a1; xr[sl+32] = a2; xr[sl+48] = a3;
        xr[64+sl] = b0; xr[64+sl+16] = b1; xr[64+sl+32] = b2v; xr[64+sl+48] = b3;
      }
      __syncthreads();
      if (tid == 0) publish(slots + 48 + s, te+1);   // ring reads done
      f32x4 acc = {0.f,0.f,0.f,0.f};
      const u16* ap = S.md.X + l15*1032 + quad*8;
#pragma unroll
      for (int kt = 0; kt < 32; ++kt) acc = mfma16(ld8(ap + kt*32), wmr[kt], acc);
#pragma unroll
      for (int r = 0; r < 4; ++r)
        S.md.par[(quad*4 + r)*68 + wave*16 + l15] = acc[r] + bias0;
      __syncthreads();
      for (int i = tid; i < 1024; i += 256){
        const int b = i >> 6, lc = i & 63, gc = s*64 + lc;
        const int bt = (bg*16 + b)*TT + te;
        const float v = S.md.par[b*68 + lc];
        if (gc >= 20 && gc < 40)        out[OW_MU1 + bt*20 + (gc-20)]  = v;
        else if (gc >= 40 && gc < 60)   out[OW_MU2 + bt*20 + (gc-40)]  = v;
        else if (gc >= 60 && gc < 80)   out[OW_S1  + bt*20 + (gc-60)]  = __expf(v);
        else if (gc >= 80 && gc < 100)  out[OW_S2  + bt*20 + (gc-80)]  = __expf(v);
        else if (gc >= 100 && gc < 120) out[OW_RHO + bt*20 + (gc-100)] = tanh_(v);
        else if (gc == 120)             out[OW_EOS + bt]               = sig_(v);
      }
      if (s == 0 && tid < 16){
        const int b = tid;
        const int bt = (bg*16 + b)*TT + te;
        float mx = -1e30f;
        for (int c = 0; c < 20; ++c) mx = fmaxf(mx, S.md.par[b*68 + c]);
        float sum = 0.f;
        for (int c = 0; c < 20; ++c) sum += __expf(S.md.par[b*68 + c] - mx);
        const float inv = 1.f/sum;
        for (int c = 0; c < 20; ++c)
          out[OW_W + bt*20 + c] = __expf(S.md.par[b*68 + c] - mx)*inv;
      }
    }
  }
}

extern "C" void kernel_launch(void* const* d_in, const int* in_sizes, int n_in,
                              void* d_out, int out_size, void* d_ws, size_t ws_size,
                              hipStream_t stream)
{
  const float* strks   = (const float*)d_in[0];
  const float* sentsm  = (const float*)d_in[3];
  const float* onehots = (const float*)d_in[4];
  const float* wprev   = (const float*)d_in[5];
  const float* Wih1 = (const float*)d_in[6];
  const float* Whh1 = (const float*)d_in[7];
  const float* bih1 = (const float*)d_in[8];
  const float* bhh1 = (const float*)d_in[9];
  const float* Wih2 = (const float*)d_in[10];
  const float* Whh2 = (const float*)d_in[11];
  const float* bih2 = (const float*)d_in[12];
  const float* bhh2 = (const float*)d_in[13];
  const float* Wsw  = (const float*)d_in[14];
  const float* bsw  = (const float*)d_in[15];
  const float* Wmdn = (const float*)d_in[16];
  const float* bmdn = (const float*)d_in[17];
  (void)in_sizes; (void)n_in; (void)out_size;

  if (ws_size < (size_t)WS_NEED) return;

  hipMemsetAsync(d_ws, 0, ZERO_BYTES, stream);
  pack_kernel<<<2048, 256, 0, stream>>>(Wih1, Whh1, bih1, bhh1, Wih2, Whh2, bih2, bhh2,
                                        Wsw, bsw, Wmdn, bmdn, onehots, (char*)d_ws);
  rnn_main<<<NBLK, 256, 0, stream>>>(strks, sentsm, wprev, (char*)d_ws, (float*)d_out);
}

// Round 5
// 5571.043 us; speedup vs baseline: 1.1962x; 1.0318x over previous
//
#include <hip/hip_runtime.h>

// Handwriting synthesis RNN — persistent fused kernel, R8.
// R8 = R7 + deadlock fix. R7 hung: role1@te polls role0 >= te+2 (w[te] is
// published during role0 step te+1), but at te=799 that demands role0 >= 801
// and role0 ended at 800. Fix: role0 runs one epilogue iteration t=TT that
// stages h1[799], computes attention (w[799]), s==0 publishes it to the
// ring, and publishes slot value 801; GEMM/gates/h-store and the strks load
// (OOB at t=800) are guarded by t<TT. All other code identical to R7:
// (1) role1 computes no attention — reads w from widened h1 ring (R1W=576);
// (2) role1 fan-in 16 blocks (128 cols, 68 AGPR-resident frags);
// (3) per-role slot lines, role0 busy-poll, others sleep-poll.

typedef unsigned short u16;
typedef unsigned int   u32;
typedef unsigned long long u64;
typedef u16   u16x8  __attribute__((ext_vector_type(8)));
typedef u32   u32x2  __attribute__((ext_vector_type(2)));
typedef u32   u32x4  __attribute__((ext_vector_type(4)));
typedef __bf16 bf16x8 __attribute__((ext_vector_type(8)));
typedef float f32x4  __attribute__((ext_vector_type(4)));

#define DEV static __device__ __forceinline__

// problem constants
#define BT   64
#define TT   800
#define UU   64
#define HH   512
#define SENT 60
#define NG   2048
#define MOUT 121
#define K1P 576    // X1 = [h1:512][strk:3][w:60][pad:1]
#define K2P 1088   // X2 = [h1:512][h2:512][w:60 @1024][strk:3 @1084][pad:1]
#define KMD 1024   // Xm = [h1:512][h2:512]
#define KSW 512
#define R1W 576    // h1 ring row: [h1:512][w:60][pad:4]

#define NBG 4
#define G1B 16
#define G2B 16
#define MDB 2
#define NBLK (NBG*(G1B+G2B+MDB))   // 136

// workspace layout (bytes)
#define OFF_BAR 0
#define OFF_H1  4096
#define OFF_H2  (OFF_H1 + 4*BT*R1W*2)
#define OFF_CM  (OFF_H2 + 4*BT*HH*2)
#define OFF_W1  (OFF_CM + 32768)
#define OFF_W2  (OFF_W1 + NG*K1P*2)
#define OFF_WSW (OFF_W2 + NG*K2P*2)
#define OFF_WMD (OFF_WSW + 32*KSW*2)
#define OFF_B1  (OFF_WMD + 128*KMD*2)
#define OFF_B2  (OFF_B1 + NG*4)
#define OFF_BSW (OFF_B2 + NG*4)
#define OFF_BMD (OFF_BSW + 256)
#define WS_NEED (OFF_BMD + 512)
#define ZERO_BYTES OFF_CM   // slots + h1/h2 rings

// output offsets (floats)
#define OW_EOS 0
#define OW_W   (BT*TT)
#define OW_MU1 (OW_W   + BT*TT*20)
#define OW_MU2 (OW_MU1 + BT*TT*20)
#define OW_S1  (OW_MU2 + BT*TT*20)
#define OW_S2  (OW_S1  + BT*TT*20)
#define OW_RHO (OW_S2  + BT*TT*20)

DEV u16 f2bf(float f){
  u32 u = __builtin_bit_cast(u32, f);
  u = (u + 0x7FFFu + ((u >> 16) & 1u)) >> 16;
  return (u16)u;
}
DEV bf16x8 ld8(const u16* p){ return __builtin_bit_cast(bf16x8, *(const u16x8*)p); }
DEV f32x4 mfma16(bf16x8 a, bf16x8 b, f32x4 c){
  return __builtin_amdgcn_mfma_f32_16x16x32_bf16(a, b, c, 0, 0, 0);
}
DEV float sig_(float x){ return 1.f/(1.f + __expf(-x)); }
DEV float tanh_(float x){
  float ax = fabsf(x);
  float e  = __expf(-2.f*ax);
  float t2 = (1.f - e)/(1.f + e);
  return x < 0.f ? -t2 : t2;
}
DEV void pin_agpr(bf16x8& v){
  u32x4 t = __builtin_bit_cast(u32x4, v);
  asm volatile("" : "+a"(t));
  v = __builtin_bit_cast(bf16x8, t);
}

// ---- L3-coherent (device-scope) memory helpers ----
DEV void ld_tile4(const u16* p, u16x8& a0, u16x8& a1, u16x8& a2, u16x8& a3){
  asm volatile(
    "global_load_dwordx4 %0, %4, off sc0 sc1\n\t"
    "global_load_dwordx4 %1, %4, off offset:256 sc0 sc1\n\t"
    "global_load_dwordx4 %2, %4, off offset:512 sc0 sc1\n\t"
    "global_load_dwordx4 %3, %4, off offset:768 sc0 sc1\n\t"
    "s_waitcnt vmcnt(0)"
    : "=&v"(a0), "=&v"(a1), "=&v"(a2), "=&v"(a3)
    : "v"(p) : "memory");
}
DEV void ld_tile8(const u16* p1, const u16* p2,
                  u16x8& a0,u16x8& a1,u16x8& a2,u16x8& a3,
                  u16x8& b0,u16x8& b1,u16x8& b2,u16x8& b3){
  asm volatile(
    "global_load_dwordx4 %0, %8, off sc0 sc1\n\t"
    "global_load_dwordx4 %1, %8, off offset:256 sc0 sc1\n\t"
    "global_load_dwordx4 %2, %8, off offset:512 sc0 sc1\n\t"
    "global_load_dwordx4 %3, %8, off offset:768 sc0 sc1\n\t"
    "global_load_dwordx4 %4, %9, off sc0 sc1\n\t"
    "global_load_dwordx4 %5, %9, off offset:256 sc0 sc1\n\t"
    "global_load_dwordx4 %6, %9, off offset:512 sc0 sc1\n\t"
    "global_load_dwordx4 %7, %9, off offset:768 sc0 sc1\n\t"
    "s_waitcnt vmcnt(0)"
    : "=&v"(a0),"=&v"(a1),"=&v"(a2),"=&v"(a3),
      "=&v"(b0),"=&v"(b1),"=&v"(b2),"=&v"(b3)
    : "v"(p1), "v"(p2) : "memory");
}
// tile8 + one dwordx2 (w-tail) in the same asm so a single vmcnt(0) covers all
DEV void ld_tile8w(const u16* p1, const u16* p2, const u16* p3,
                   u16x8& a0,u16x8& a1,u16x8& a2,u16x8& a3,
                   u16x8& b0,u16x8& b1,u16x8& b2,u16x8& b3, u32x2& w){
  asm volatile(
    "global_load_dwordx4 %0, %9, off sc0 sc1\n\t"
    "global_load_dwordx4 %1, %9, off offset:256 sc0 sc1\n\t"
    "global_load_dwordx4 %2, %9, off offset:512 sc0 sc1\n\t"
    "global_load_dwordx4 %3, %9, off offset:768 sc0 sc1\n\t"
    "global_load_dwordx4 %4, %10, off sc0 sc1\n\t"
    "global_load_dwordx4 %5, %10, off offset:256 sc0 sc1\n\t"
    "global_load_dwordx4 %6, %10, off offset:512 sc0 sc1\n\t"
    "global_load_dwordx4 %7, %10, off offset:768 sc0 sc1\n\t"
    "global_load_dwordx2 %8, %11, off sc0 sc1\n\t"
    "s_waitcnt vmcnt(0)"
    : "=&v"(a0),"=&v"(a1),"=&v"(a2),"=&v"(a3),
      "=&v"(b0),"=&v"(b1),"=&v"(b2),"=&v"(b3),"=&v"(w)
    : "v"(p1), "v"(p2), "v"(p3) : "memory");
}
DEV void st_dword_sc(u32* p, u32 v){
  asm volatile("global_store_dword %0, %1, off sc0 sc1" :: "v"(p), "v"(v) : "memory");
}
DEV void st_dwordx2_sc(u32* p, u32 a, u32 b){
  u32x2 v = {a, b};
  asm volatile("global_store_dwordx2 %0, %1, off sc0 sc1" :: "v"(p), "v"(v) : "memory");
}
DEV void vmwait0(){ asm volatile("s_waitcnt vmcnt(0)" ::: "memory"); }

// tag-slot barrier: per group, 256 u32 (1KB). role0 slots [0..15] (line 0),
// role1 [32..47], role2 [56..57]. Producer stores step+1 (monotone). Only
// wave0 polls: lane-indexed sc0sc1 load + __all(); other waves wait at the
// following __syncthreads. slp=false => busy poll (binding chain).
DEV void poll_slots(const u32* slots, int T0, int T1, int T2, bool slp){
  if (T0 <= 0 && T1 <= 0 && T2 <= 0) return;
  const int lane = threadIdx.x & 63;
  int thr = (int)0x80000000;
  int idx = 63;
  if (lane < 16)                      { thr = T0; idx = lane; }
  else if (lane >= 32 && lane < 48)   { thr = T1; idx = lane; }
  else if (lane == 56 || lane == 57)  { thr = T2; idx = lane; }
  const u32* p = slots + idx;
  for(;;){
    u32 v;
    asm volatile("global_load_dword %0, %1, off sc0 sc1\n\ts_waitcnt vmcnt(0)"
      : "=&v"(v) : "v"(p) : "memory");
    if (__all((int)v >= thr)) return;
    if (slp) __builtin_amdgcn_s_sleep(2);
  }
}
DEV void publish(u32* p, int v){
  asm volatile("global_store_dword %0, %1, off sc0 sc1" :: "v"(p), "v"((u32)v) : "memory");
}

// ---------------- weight/bias/mask pre-pack ----------
__global__ __launch_bounds__(256) void pack_kernel(
    const float* __restrict__ Wih1, const float* __restrict__ Whh1,
    const float* __restrict__ bih1, const float* __restrict__ bhh1,
    const float* __restrict__ Wih2, const float* __restrict__ Whh2,
    const float* __restrict__ bih2, const float* __restrict__ bhh2,
    const float* __restrict__ Wsw,  const float* __restrict__ bsw,
    const float* __restrict__ Wmdn, const float* __restrict__ bmdn,
    const float* __restrict__ onehots, char* __restrict__ ws)
{
  u16* Wp1  = (u16*)(ws + OFF_W1);
  u16* Wp2  = (u16*)(ws + OFF_W2);
  u16* Wswp = (u16*)(ws + OFF_WSW);
  u16* Wmdp = (u16*)(ws + OFF_WMD);
  float* b1p  = (float*)(ws + OFF_B1);
  float* b2p  = (float*)(ws + OFF_B2);
  float* bswp = (float*)(ws + OFF_BSW);
  float* bmdp = (float*)(ws + OFF_BMD);
  u64* cmask = (u64*)(ws + OFF_CM);

  const int SA = NG*K1P, SB = NG*K2P, SC = 32*KSW, SD = 128*KMD;
  const int SE = NG + NG + 32 + 128, SF = BT*SENT;
  const int total = SA+SB+SC+SD+SE+SF;
  for (int i = blockIdx.x*blockDim.x + threadIdx.x; i < total; i += gridDim.x*blockDim.x){
    if (i < SA){
      const int n = i / K1P, k = i - n*K1P;
      const int r = (n&3)*HH + (n>>2);
      float f;
      if (k < 512)      f = Whh1[r*HH + k];
      else if (k < 515) f = Wih1[r*63 + (k-512)];
      else if (k < 575) f = Wih1[r*63 + 3 + (k-515)];
      else              f = 0.f;
      Wp1[i] = f2bf(f);
    } else if (i < SA+SB){
      const int j = i - SA;
      const int n = j / K2P, k = j - n*K2P;
      const int r = (n&3)*HH + (n>>2);
      float f;
      if (k < 512)       f = Wih2[r*575 + 3 + k];           // h1
      else if (k < 1024) f = Whh2[r*HH + (k-512)];          // h2
      else if (k < 1084) f = Wih2[r*575 + 515 + (k-1024)];  // w
      else if (k < 1087) f = Wih2[r*575 + (k-1084)];        // strk
      else               f = 0.f;
      Wp2[j] = f2bf(f);
    } else if (i < SA+SB+SC){
      const int j = i - SA - SB;
      const int n = j >> 9, k = j & 511;
      Wswp[j] = f2bf(n < 30 ? Wsw[n*KSW + k] : 0.f);
    } else if (i < SA+SB+SC+SD){
      const int j = i - SA - SB - SC;
      const int n = j >> 10, k = j & 1023;
      float f = 0.f;
      if (n < MOUT) f = (k < 512) ? Wmdn[n*1536 + k]
                                  : (Wmdn[n*1536 + 512 + (k-512)] + Wmdn[n*1536 + 1024 + (k-512)]);
      Wmdp[j] = f2bf(f);
    } else if (i < SA+SB+SC+SD+SE){
      int j = i - SA - SB - SC - SD;
      if (j < NG){ const int r=(j&3)*HH+(j>>2); b1p[j] = bih1[r] + bhh1[r]; }
      else if ((j -= NG) < NG){ const int r=(j&3)*HH+(j>>2); b2p[j] = bih2[r] + bhh2[r]; }
      else if ((j -= NG) < 32){ bswp[j] = (j < 30) ? bsw[j] : 0.f; }
      else { j -= 32; bmdp[j] = (j < MOUT) ? bmdn[j] : 0.f; }
    } else {
      const int j = i - SA - SB - SC - SD - SE;
      const int b = j / SENT, c = j - b*SENT;
      const float* oh = onehots + b*UU*SENT + c;
      u64 m = 0;
#pragma unroll 1
      for (int u = 0; u < UU; ++u) if (oh[u*SENT] > 0.5f) m |= (1ull << u);
      cmask[j] = m;
    }
  }
}

// ---------------- LDS layouts ----------------
struct G1S {
  float c[512]; float kk[160];
  u16   X1[16*584];
  union { float gates[4*16*33]; struct { float pp[1024]; float phi[1024]; } a; } u;
  float aa[160], bb[160];
  float smv[1024];
  u64   cm[960];
};
struct G2S {        // role1: no attention scratch anymore
  float c[512];
  u16   X2[16*1096];
  float gates[4*16*33];
};
struct MDS { u16 X[16*1032]; float par[16*68]; };
union alignas(16) BigU { G1S g1; G2S g2; MDS md; };

struct WswF { bf16x8 f[8]; };

// attention for step (tw-1): p = h1 @ Wsw^T from staged X (cols 0..511),
// kappa accumulates in kk, writes bf16 w into the X tile tail at tailoff.
// tw==0 => copy wprev into tail. (role0 only)
DEV void attn_tail(int tw, int bg, u16* X, int xstride, int tailoff,
                   float* pp, float* aa, float* bb, float* kk, float* phi,
                   const float* smv, const u64* cmL, WswF wf,
                   float bswa, float bswb, float bswk,
                   const float* __restrict__ wprev)
{
  const int tid = threadIdx.x;
  if (tw == 0){
    for (int i = tid; i < 16*SENT; i += 256){
      const int b = i / SENT, c = i - b*SENT;
      X[b*xstride + tailoff + c] = f2bf(wprev[(bg*16 + b)*SENT + c]);
    }
    return;
  }
  const int wave = tid >> 6, lane = tid & 63;
  const int quad = lane >> 4, l15 = lane & 15;
  {
    f32x4 acc = {0.f,0.f,0.f,0.f};
    const u16* ap = X + l15*xstride + quad*8 + (wave>>1)*256;
#pragma unroll
    for (int j = 0; j < 8; ++j) acc = mfma16(ld8(ap + j*32), wf.f[j], acc);
    float* dst = pp + (wave>>1)*512;
    const int n = (wave&1)*16 + l15;
#pragma unroll
    for (int r = 0; r < 4; ++r) dst[(quad*4 + r)*32 + n] = acc[r];
  }
  __syncthreads();
  if (tid < 160){
    const int b = tid/10, j = tid - b*10;
    aa[tid] = __expf(pp[b*32 + j]      + pp[512 + b*32 + j]      + bswa);
    bb[tid] = __expf(pp[b*32 + 10 + j] + pp[512 + b*32 + 10 + j] + bswb);
    kk[tid] += __expf(pp[b*32 + 20 + j] + pp[512 + b*32 + 20 + j] + bswk);
  }
  __syncthreads();
  for (int i = tid; i < 1024; i += 256){
    const int b = i >> 6, u = i & 63;
    const float uf = (float)u;
    float acc = 0.f;
#pragma unroll
    for (int j = 0; j < 10; ++j){
      float d = kk[b*10 + j] - uf;
      acc = fmaf(aa[b*10 + j], __expf(-bb[b*10 + j]*d*d), acc);
    }
    phi[i] = acc * smv[i];
  }
  __syncthreads();
  for (int i = tid; i < 16*SENT; i += 256){
    const int b = i / SENT, c = i - b*SENT;
    u64 m = cmL[i];
    float acc = 0.f;
    while (m){ const int u = __builtin_ctzll(m); m &= m - 1; acc += phi[b*64 + u]; }
    X[b*xstride + tailoff + c] = f2bf(acc);
  }
}

// ---------------- main persistent kernel ----------------
__global__ __attribute__((amdgpu_waves_per_eu(1,1))) __launch_bounds__(256)
void rnn_main(
    const float* __restrict__ strks, const float* __restrict__ sm,
    const float* __restrict__ wprev, char* __restrict__ ws,
    float* __restrict__ out)
{
  u32* bar   = (u32*)(ws + OFF_BAR);
  u16* h1pub = (u16*)(ws + OFF_H1);
  u16* h2pub = (u16*)(ws + OFF_H2);
  const u64* cmask = (const u64*)(ws + OFF_CM);
  const u16* Wp1  = (const u16*)(ws + OFF_W1);
  const u16* Wp2  = (const u16*)(ws + OFF_W2);
  const u16* Wswp = (const u16*)(ws + OFF_WSW);
  const u16* Wmdp = (const u16*)(ws + OFF_WMD);
  const float* b1p  = (const float*)(ws + OFF_B1);
  const float* b2p  = (const float*)(ws + OFF_B2);
  const float* bswp = (const float*)(ws + OFF_BSW);
  const float* bmdp = (const float*)(ws + OFF_BMD);

  __shared__ BigU S;

  const int bid = blockIdx.x, tid = threadIdx.x;
  const int wave = tid >> 6, lane = tid & 63;
  const int quad = lane >> 4, l15 = lane & 15;
  const int sb = tid >> 4, sl = tid & 15;

  if (bid < NBG*G1B){
    // ===== role 0: LSTM1 step t; 16 blocks/group, 128 gate cols each =====
    // Runs TT+1 iterations: the t==TT epilogue only computes attention
    // (w[TT-1]) and publishes it, so role1's te+2 poll closes at te=TT-1.
    const int bg = bid >> 4, s = bid & 15;
    u32* slots = bar + bg*256;
    bf16x8 w1r[36];
    const int n0 = s*128 + wave*32 + l15, n1 = n0 + 16;
#pragma unroll
    for (int kt = 0; kt < 18; ++kt){
      w1r[2*kt]   = ld8(Wp1 + n0*K1P + quad*8 + kt*32);
      w1r[2*kt+1] = ld8(Wp1 + n1*K1P + quad*8 + kt*32);
    }
#pragma unroll
    for (int i = 0; i < 36; ++i) pin_agpr(w1r[i]);
    WswF wf;
    { const int nsw = (wave&1)*16 + l15, k0 = (wave>>1)*8;
#pragma unroll
      for (int j = 0; j < 8; ++j) wf.f[j] = ld8(Wswp + nsw*KSW + quad*8 + (k0+j)*32);
#pragma unroll
      for (int j = 0; j < 8; ++j) pin_agpr(wf.f[j]);
    }
    const float bias0 = b1p[n0], bias1 = b1p[n1];
    float bswa = 0.f, bswb = 0.f, bswk = 0.f;
    if (tid < 160){ const int j = tid % 10; bswa = bswp[j]; bswb = bswp[10+j]; bswk = bswp[20+j]; }
    for (int i = tid; i < 512; i += 256) S.g1.c[i] = 0.f;
    if (tid < 160) S.g1.kk[tid] = 0.f;
    for (int i = tid; i < 1024; i += 256) S.g1.smv[i] = sm[(bg*16 + (i>>6))*UU + (i&63)];
    for (int i = tid; i < 960;  i += 256) S.g1.cm[i]  = cmask[(bg*16 + i/60)*SENT + i%60];
    if (sl == 0) S.g1.X1[sb*584 + 575] = 0;
    __syncthreads();

    for (int t = 0; t <= TT; ++t){
      float sv = (sl < 3 && t < TT) ? strks[((bg*16 + sb)*TT + t)*3 + sl] : 0.f;
      if (wave == 0) poll_slots(slots, t, t-3, t-3, false);
      __syncthreads();
      const u16* h1prev = h1pub + ((t+3)&3)*(BT*R1W);
      {
        u16x8 a0,a1,a2,a3;
        ld_tile4(h1prev + (bg*16 + sb)*R1W + sl*8, a0,a1,a2,a3);
        u16x8* xr = (u16x8*)(S.g1.X1 + sb*584);
        xr[sl] = a0; xr[sl+16] = a1; xr[sl+32] = a2; xr[sl+48] = a3;
        if (sl < 3) S.g1.X1[sb*584 + 512 + sl] = f2bf(sv);
      }
      __syncthreads();
      attn_tail(t, bg, S.g1.X1, 584, 515, S.g1.u.a.pp, S.g1.aa, S.g1.bb, S.g1.kk,
                S.g1.u.a.phi, S.g1.smv, S.g1.cm, wf, bswa, bswb, bswk, wprev);
      __syncthreads();
      if (t < TT){
        f32x4 acc0 = {0.f,0.f,0.f,0.f}, acc1 = {0.f,0.f,0.f,0.f};
        const u16* ap = S.g1.X1 + l15*584 + quad*8;
#pragma unroll
        for (int kt = 0; kt < 18; ++kt){
          bf16x8 av = ld8(ap + kt*32);
          acc0 = mfma16(av, w1r[2*kt],   acc0);
          acc1 = mfma16(av, w1r[2*kt+1], acc1);
        }
        {
          const int gpl = l15 & 3, cbase = wave*8 + (l15 >> 2);
#pragma unroll
          for (int r = 0; r < 4; ++r){
            float* gp = S.g1.u.gates + gpl*528 + (quad*4 + r)*33 + cbase;
            gp[0] = acc0[r] + bias0;
            gp[4] = acc1[r] + bias1;
          }
        }
        __syncthreads();
        u16* h1cur = h1pub + (t&3)*(BT*R1W);
        {
          const int row = tid >> 4, cp = tid & 15;
          const float* gb = S.g1.u.gates + row*33 + 2*cp;
          const int ci = row*32 + 2*cp;
          float c0 = sig_(gb[528])*S.g1.c[ci]   + sig_(gb[0])*tanh_(gb[1056]);
          float c1 = sig_(gb[529])*S.g1.c[ci+1] + sig_(gb[1])*tanh_(gb[1057]);
          S.g1.c[ci] = c0; S.g1.c[ci+1] = c1;
          u32 v = (u32)f2bf(sig_(gb[1584])*tanh_(c0)) |
                  ((u32)f2bf(sig_(gb[1585])*tanh_(c1)) << 16);
          st_dword_sc((u32*)(h1cur + (bg*16 + row)*R1W + s*32 + 2*cp), v);
        }
      }
      if (s == 0 && tid < 240){
        // publish w[t-1] (attn tail, still in X1) into ring slot (t-1)&3
        u16* wring = h1pub + ((t+3)&3)*(BT*R1W);
        const int b = tid/15, j = tid - b*15;
        const u16* xw = S.g1.X1 + b*584 + 515 + 4*j;
        u32 v0 = (u32)xw[0] | ((u32)xw[1] << 16);
        u32 v1 = (u32)xw[2] | ((u32)xw[3] << 16);
        st_dwordx2_sc((u32*)(wring + (bg*16 + b)*R1W + 512 + 4*j), v0, v1);
      }
      vmwait0();
      __syncthreads();
      if (tid == 0) publish(slots + s, t+1);
    }
  }
  else if (bid < NBG*(G1B+G2B)){
    // ===== role 1: LSTM2 step te; 16 blocks/group, 128 gate cols, NO attn
    const int b2 = bid - NBG*G1B, bg = b2 >> 4, s = b2 & 15;
    u32* slots = bar + bg*256;
    bf16x8 w2r[68];
    const int n0 = s*128 + wave*32 + l15, n1 = n0 + 16;
#pragma unroll
    for (int kt = 0; kt < 34; ++kt){
      w2r[2*kt]   = ld8(Wp2 + n0*K2P + quad*8 + kt*32);
      w2r[2*kt+1] = ld8(Wp2 + n1*K2P + quad*8 + kt*32);
    }
#pragma unroll
    for (int i = 0; i < 68; ++i) pin_agpr(w2r[i]);
    const float bias0 = b2p[n0], bias1 = b2p[n1];
    for (int i = tid; i < 512; i += 256) S.g2.c[i] = 0.f;
    if (sl == 0) S.g2.X2[sb*1096 + 1087] = 0;
    __syncthreads();

    for (int te = 0; te < TT; ++te){
      float sv = (sl < 3) ? strks[((bg*16 + sb)*TT + te)*3 + sl] : 0.f;
      if (wave == 0) poll_slots(slots, te+2, te, te-3, true);
      __syncthreads();
      const u16* h1te = h1pub + (te&3)*(BT*R1W);
      const u16* h2pv = h2pub + ((te+3)&3)*(BT*HH);
      {
        u16x8 a0,a1,a2,a3,b0,b1,b2v,b3; u32x2 wv;
        ld_tile8w(h1te + (bg*16 + sb)*R1W + sl*8,
                  h2pv + (bg*16 + sb)*HH  + sl*8,
                  h1te + (bg*16 + sb)*R1W + 512 + sl*4,
                  a0,a1,a2,a3, b0,b1,b2v,b3, wv);
        u16x8* xr = (u16x8*)(S.g2.X2 + sb*1096);
        xr[sl] = a0; xr[sl+16] = a1; xr[sl+32] = a2; xr[sl+48] = a3;
        xr[64+sl] = b0; xr[64+sl+16] = b1; xr[64+sl+32] = b2v; xr[64+sl+48] = b3;
        if (sl < 15){
          u32* wp = (u32*)(S.g2.X2 + sb*1096 + 1024 + 4*sl);
          wp[0] = wv.x; wp[1] = wv.y;
        }
        if (sl < 3) S.g2.X2[sb*1096 + 1084 + sl] = f2bf(sv);
      }
      __syncthreads();
      f32x4 acc0 = {0.f,0.f,0.f,0.f}, acc1 = {0.f,0.f,0.f,0.f};
      const u16* ap = S.g2.X2 + l15*1096 + quad*8;
#pragma unroll
      for (int kt = 0; kt < 34; ++kt){
        bf16x8 av = ld8(ap + kt*32);
        acc0 = mfma16(av, w2r[2*kt],   acc0);
        acc1 = mfma16(av, w2r[2*kt+1], acc1);
      }
      {
        const int gpl = l15 & 3, cbase = wave*8 + (l15 >> 2);
#pragma unroll
        for (int r = 0; r < 4; ++r){
          float* gp = S.g2.gates + gpl*528 + (quad*4 + r)*33 + cbase;
          gp[0] = acc0[r] + bias0;
          gp[4] = acc1[r] + bias1;
        }
      }
      __syncthreads();
      u16* h2cur = h2pub + (te&3)*(BT*HH);
      {
        const int row = tid >> 4, cp = tid & 15;
        const float* gb = S.g2.gates + row*33 + 2*cp;
        const int ci = row*32 + 2*cp;
        float c0 = sig_(gb[528])*S.g2.c[ci]   + sig_(gb[0])*tanh_(gb[1056]);
        float c1 = sig_(gb[529])*S.g2.c[ci+1] + sig_(gb[1])*tanh_(gb[1057]);
        S.g2.c[ci] = c0; S.g2.c[ci+1] = c1;
        u32 v = (u32)f2bf(sig_(gb[1584])*tanh_(c0)) |
                ((u32)f2bf(sig_(gb[1585])*tanh_(c1)) << 16);
        st_dword_sc((u32*)(h2cur + (bg*16 + row)*HH + s*32 + 2*cp), v);
      }
      vmwait0();
      __syncthreads();
      if (tid == 0) publish(slots + 32 + s, te+1);
    }
  }
  else {
    // ===== role 2: MDN head, step te (signals after staging) =====
    const int b2 = bid - NBG*(G1B+G2B), bg = b2 >> 1, s = b2 & 1;
    u32* slots = bar + bg*256;
    bf16x8 wmr[32];
    const int n0 = s*64 + wave*16 + l15;
#pragma unroll
    for (int kt = 0; kt < 32; ++kt) wmr[kt] = ld8(Wmdp + n0*KMD + quad*8 + kt*32);
#pragma unroll
    for (int i = 0; i < 32; ++i) pin_agpr(wmr[i]);
    const float bias0 = bmdp[n0];
    __syncthreads();

    for (int te = 0; te < TT; ++te){
      if (wave == 0) poll_slots(slots, 0, te+1, 0, true);
      __syncthreads();
      const u16* h1te = h1pub + (te&3)*(BT*R1W);
      const u16* h2te = h2pub + (te&3)*(BT*HH);
      {
        u16x8 a0,a1,a2,a3,b0,b1,b2v,b3;
        ld_tile8(h1te + (bg*16 + sb)*R1W + sl*8, h2te + (bg*16 + sb)*HH + sl*8,
                 a0,a1,a2,a3, b0,b1,b2v,b3);
        u16x8* xr = (u16x8*)(S.md.X + sb*1032);
        xr[sl] = a0; xr[sl+16] = a1; xr[sl+32] = a2; xr[sl+48] = a3;
        xr[64+sl] = b0; xr[64+sl+16] = b1; xr[64+sl+32] = b2v; xr[64+sl+48] = b3;
      }
      __syncthreads();
      if (tid == 0) publish(slots + 56 + s, te+1);   // ring reads done
      f32x4 acc = {0.f,0.f,0.f,0.f};
      const u16* ap = S.md.X + l15*1032 + quad*8;
#pragma unroll
      for (int kt = 0; kt < 32; ++kt) acc = mfma16(ld8(ap + kt*32), wmr[kt], acc);
#pragma unroll
      for (int r = 0; r < 4; ++r)
        S.md.par[(quad*4 + r)*68 + wave*16 + l15] = acc[r] + bias0;
      __syncthreads();
      for (int i = tid; i < 1024; i += 256){
        const int b = i >> 6, lc = i & 63, gc = s*64 + lc;
        const int bt = (bg*16 + b)*TT + te;
        const float v = S.md.par[b*68 + lc];
        if (gc >= 20 && gc < 40)        out[OW_MU1 + bt*20 + (gc-20)]  = v;
        else if (gc >= 40 && gc < 60)   out[OW_MU2 + bt*20 + (gc-40)]  = v;
        else if (gc >= 60 && gc < 80)   out[OW_S1  + bt*20 + (gc-60)]  = __expf(v);
        else if (gc >= 80 && gc < 100)  out[OW_S2  + bt*20 + (gc-80)]  = __expf(v);
        else if (gc >= 100 && gc < 120) out[OW_RHO + bt*20 + (gc-100)] = tanh_(v);
        else if (gc == 120)             out[OW_EOS + bt]               = sig_(v);
      }
      if (s == 0 && tid < 16){
        const int b = tid;
        const int bt = (bg*16 + b)*TT + te;
        float mx = -1e30f;
        for (int c = 0; c < 20; ++c) mx = fmaxf(mx, S.md.par[b*68 + c]);
        float sum = 0.f;
        for (int c = 0; c < 20; ++c) sum += __expf(S.md.par[b*68 + c] - mx);
        const float inv = 1.f/sum;
        for (int c = 0; c < 20; ++c)
          out[OW_W + bt*20 + c] = __expf(S.md.par[b*68 + c] - mx)*inv;
      }
    }
  }
}

extern "C" void kernel_launch(void* const* d_in, const int* in_sizes, int n_in,
                              void* d_out, int out_size, void* d_ws, size_t ws_size,
                              hipStream_t stream)
{
  const float* strks   = (const float*)d_in[0];
  const float* sentsm  = (const float*)d_in[3];
  const float* onehots = (const float*)d_in[4];
  const float* wprev   = (const float*)d_in[5];
  const float* Wih1 = (const float*)d_in[6];
  const float* Whh1 = (const float*)d_in[7];
  const float* bih1 = (const float*)d_in[8];
  const float* bhh1 = (const float*)d_in[9];
  const float* Wih2 = (const float*)d_in[10];
  const float* Whh2 = (const float*)d_in[11];
  const float* bih2 = (const float*)d_in[12];
  const float* bhh2 = (const float*)d_in[13];
  const float* Wsw  = (const float*)d_in[14];
  const float* bsw  = (const float*)d_in[15];
  const float* Wmdn = (const float*)d_in[16];
  const float* bmdn = (const float*)d_in[17];
  (void)in_sizes; (void)n_in; (void)out_size;

  if (ws_size < (size_t)WS_NEED) return;

  hipMemsetAsync(d_ws, 0, ZERO_BYTES, stream);
  pack_kernel<<<2048, 256, 0, stream>>>(Wih1, Whh1, bih1, bhh1, Wih2, Whh2, bih2, bhh2,
                                        Wsw, bsw, Wmdn, bmdn, onehots, (char*)d_ws);
  rnn_main<<<NBLK, 256, 0, stream>>>(strks, sentsm, wprev, (char*)d_ws, (float*)d_out);
}